// Round 6
// baseline (1775.716 us; speedup 1.0000x reference)
//
#include <hip/hip_runtime.h>
#include <stdint.h>

// GCN multi-branch, round 6.
// relu((L@x)@W+b) == relu(L@(x@W)+b): small input-side W-GEMMs + big L-GEMMs.
// big: 256x256 tile, 8 waves, 32x32x16 MFMA, BK=64, 8-phase counted-vmcnt schedule:
//   A (fp32) reg-staged 2-slot w/ 4-phase flight + swizzled ds_write,
//   B (bf16) global_load_lds pre-swizzled source, 3-slot ring (2-tile lead),
//   vmcnt(12) at phases 4/8 only, setprio around MFMA clusters, LDS = 160KB.

typedef short bf16x8 __attribute__((ext_vector_type(8)));
typedef float f32x4  __attribute__((ext_vector_type(4)));
typedef float f32x16 __attribute__((ext_vector_type(16)));

static __device__ __forceinline__ unsigned short f2bf(float f) {
  __bf16 h = (__bf16)f;
  return __builtin_bit_cast(unsigned short, h);
}
static __device__ __forceinline__ unsigned int pack2(float a, float b) {
  return (unsigned int)f2bf(a) | ((unsigned int)f2bf(b) << 16);
}
static __device__ __forceinline__ bf16x8 cvt8(float4 lo, float4 hi) {
  bf16x8 r;
  r[0] = (short)f2bf(lo.x); r[1] = (short)f2bf(lo.y);
  r[2] = (short)f2bf(lo.z); r[3] = (short)f2bf(lo.w);
  r[4] = (short)f2bf(hi.x); r[5] = (short)f2bf(hi.y);
  r[6] = (short)f2bf(hi.z); r[7] = (short)f2bf(hi.w);
  return r;
}

#define GLOAD16(g, l)                                                                  \
  __builtin_amdgcn_global_load_lds((const __attribute__((address_space(1))) void*)(g), \
                                   (__attribute__((address_space(3))) void*)(l), 16, 0, 0)

// ---------------------------------------------------------------- prep: W[fi][fo] -> WT bf16 [fo][fi]
struct WPtrs { const float* w[8]; };
__global__ __launch_bounds__(256)
void prep_w(WPtrs p, unsigned short* __restrict__ wt) {
  const int s = blockIdx.x;
  const float* W = p.w[s];
  unsigned short* dst = wt + s * 16384;
  for (int i = threadIdx.x; i < 16384; i += 256) {
    const int fi = i >> 7, fo = i & 127;
    dst[fo * 128 + fi] = f2bf(W[i]);
  }
}

// ---------------------------------------------------------------- small GEMM: Z = A @ W  (K=128)
template <int AFP32>
__global__ __launch_bounds__(256)
void small_gemm(const float* __restrict__ x, const unsigned short* __restrict__ H1m,
                const unsigned short* __restrict__ WT, unsigned short* __restrict__ Z) {
  __shared__ unsigned short Sa[128 * 136];

  const int t = threadIdx.x, lane = t & 63, wave = t >> 6;
  const int l15 = lane & 15, lk = (lane >> 4) * 8;
  const int wm = (wave >> 1) * 64, wn = (wave & 1) * 64;
  const int mt = blockIdx.x, br = blockIdx.y;
  const int batch = mt >> 6, node0 = (mt & 63) * 128;

  {
    const int row = t >> 1, seg = (t & 1) * 64;
    if (AFP32) {
      const float4* src = (const float4*)(x + ((size_t)batch * 8192 + node0 + row) * 128 + seg);
      uint4* dst = (uint4*)&Sa[row * 136 + seg];
#pragma unroll
      for (int i = 0; i < 8; ++i) {
        float4 a = src[i * 2], b = src[i * 2 + 1];
        uint4 v;
        v.x = pack2(a.x, a.y); v.y = pack2(a.z, a.w);
        v.z = pack2(b.x, b.y); v.w = pack2(b.z, b.w);
        dst[i] = v;
      }
    } else {
      const uint4* src = (const uint4*)(H1m + ((size_t)(br * 4 + batch) * 8192 + node0 + row) * 128 + seg);
      uint4* dst = (uint4*)&Sa[row * 136 + seg];
#pragma unroll
      for (int i = 0; i < 8; ++i) dst[i] = src[i];
    }
  }
  __syncthreads();

  const unsigned short* WTb = WT + (size_t)(2 * br + (AFP32 ? 0 : 1)) * 16384;
  f32x4 acc[4][4];
#pragma unroll
  for (int i = 0; i < 4; ++i)
#pragma unroll
    for (int j = 0; j < 4; ++j) acc[i][j] = f32x4{0.f, 0.f, 0.f, 0.f};

#pragma unroll
  for (int kk = 0; kk < 4; ++kk) {
    bf16x8 av[4], wv[4];
#pragma unroll
    for (int mi = 0; mi < 4; ++mi)
      av[mi] = *(const bf16x8*)&Sa[(wm + mi * 16 + l15) * 136 + kk * 32 + lk];
#pragma unroll
    for (int ni = 0; ni < 4; ++ni)
      wv[ni] = *(const bf16x8*)&WTb[(wn + ni * 16 + l15) * 128 + kk * 32 + lk];
#pragma unroll
    for (int mi = 0; mi < 4; ++mi)
#pragma unroll
      for (int ni = 0; ni < 4; ++ni)
        acc[mi][ni] = __builtin_amdgcn_mfma_f32_16x16x32_bf16(av[mi], wv[ni], acc[mi][ni], 0, 0, 0);
  }

#pragma unroll
  for (int mi = 0; mi < 4; ++mi) {
#pragma unroll
    for (int ni = 0; ni < 4; ++ni) {
      const int row0 = wm + mi * 16 + (lane >> 4) * 4;
      const int col  = wn + ni * 16 + l15;
      uint2 pv;
      pv.x = pack2(acc[mi][ni][0], acc[mi][ni][1]);
      pv.y = pack2(acc[mi][ni][2], acc[mi][ni][3]);
      *(uint2*)(Z + ((size_t)br * 512 + batch * 128 + col) * 8192 + node0 + row0) = pv;
    }
  }
}

// ---------------------------------------------------------------- big GEMM: Dst = relu(L @ Z^T + b)
struct BigArgs {
  const float* L[4];
  const float* bias[4];
  const unsigned short* Z;  // [br][512][8192] bf16 n-major
  void* Dst;                // LAYER0: H1 bf16 m-major; LAYER1: out fp32
};

template <int LAYER>
__global__ __launch_bounds__(512)
void big_gemm(BigArgs a) {
  extern __shared__ char smem[];

  const int t = threadIdx.x, lane = t & 63, wave = t >> 6;
  const int l31 = lane & 31, hk = lane >> 5;
  const int wm = (wave >> 2) * 128, wn = (wave & 3) * 64;

  const int bid = blockIdx.x;
  const int work = (bid & 7) * 32 + (bid >> 3);   // XCD-chunked, bijective (256 % 8 == 0)
  const int nb = work & 1, mt = (work >> 1) & 31, br = work >> 6;
  const int mbase = mt * 256;

  const float* A = a.L[br];
  const float* bias = a.bias[br];
  const unsigned short* Zb = a.Z + (size_t)br * (512 * 8192);

  // A staging (reg -> swizzled ds_write): thread -> row t>>1, k-half ah
  const int arow = t >> 1, ah = t & 1;
  const float* aG = A + (size_t)(mbase + arow) * 8192 + ah * 32;
  const int awBase = arow * 128, awKey = arow & 7, ah4 = ah * 4;
  // B staging (global_load_lds, pre-swizzled source)
  const int brow = lane >> 3;
  const unsigned short* bG = Zb + (size_t)(nb * 256 + wave * 32 + brow) * 8192
                                + ((lane & 7) ^ (brow & 7)) * 8;
  const int bW = wave * 4096;  // wave's 32-row LDS window (bytes)

  // fragment-read bases (all xor keys reduce to l31&7)
  const int aBase = (wm + l31) * 128;
  const int bBase = (wn + l31) * 128;
  const int key7 = l31 & 7;

  f32x16 c00{}, c01{}, c10{}, c11{}, c20{}, c21{}, c30{}, c31{};
  float4 E[8], O[8];
  bf16x8 av0, av1, av2, av3, bv0, bv1;

#define A_LD(SET, KOFF, q) do {                              \
    const float* _p = aG + (KOFF) + (q) * 8;                 \
    SET[2 * (q)]     = *(const float4*)_p;                   \
    SET[2 * (q) + 1] = *(const float4*)(_p + 4); } while (0)

#define A_WR(SET, SLOT, q) do {                              \
    *(bf16x8*)(smem + (SLOT) * 32768 + awBase +              \
               (((ah4 + (q)) ^ awKey) * 16)) =               \
        cvt8(SET[2 * (q)], SET[2 * (q) + 1]); } while (0)

#define B_ST(KOFF, BOFFD, q) do {                            \
    const unsigned short* _p = bG + (KOFF) + (size_t)(q) * 8 * 8192;  \
    GLOAD16(_p, smem + 65536 + (BOFFD) + bW + (q) * 1024); } while (0)

#define RD_FRAGS(ASLOT, BOFF, q) do {                        \
    const int _ch = (((2 * (q)) + hk) ^ key7) * 16;          \
    const char* _ap = smem + (ASLOT) + aBase + _ch;          \
    av0 = *(const bf16x8*)(_ap);                             \
    av1 = *(const bf16x8*)(_ap + 4096);                      \
    av2 = *(const bf16x8*)(_ap + 8192);                      \
    av3 = *(const bf16x8*)(_ap + 12288);                     \
    const char* _bp = smem + 65536 + (BOFF) + bBase + _ch;   \
    bv0 = *(const bf16x8*)(_bp);                             \
    bv1 = *(const bf16x8*)(_bp + 4096); } while (0)

#define DO_MFMA() do {                                                     \
    __builtin_amdgcn_s_setprio(1);                                         \
    c00 = __builtin_amdgcn_mfma_f32_32x32x16_bf16(av0, bv0, c00, 0, 0, 0); \
    c01 = __builtin_amdgcn_mfma_f32_32x32x16_bf16(av0, bv1, c01, 0, 0, 0); \
    c10 = __builtin_amdgcn_mfma_f32_32x32x16_bf16(av1, bv0, c10, 0, 0, 0); \
    c11 = __builtin_amdgcn_mfma_f32_32x32x16_bf16(av1, bv1, c11, 0, 0, 0); \
    c20 = __builtin_amdgcn_mfma_f32_32x32x16_bf16(av2, bv0, c20, 0, 0, 0); \
    c21 = __builtin_amdgcn_mfma_f32_32x32x16_bf16(av2, bv1, c21, 0, 0, 0); \
    c30 = __builtin_amdgcn_mfma_f32_32x32x16_bf16(av3, bv0, c30, 0, 0, 0); \
    c31 = __builtin_amdgcn_mfma_f32_32x32x16_bf16(av3, bv1, c31, 0, 0, 0); \
    __builtin_amdgcn_s_setprio(0); } while (0)

#define VM12 asm volatile("s_waitcnt vmcnt(12)" ::: "memory")
#define VM0  asm volatile("s_waitcnt vmcnt(0)" ::: "memory")
#define NOSTG (void)0

#define PHASE(ASLOT, BOFF, q, STAGES, VM) do {               \
    STAGES;                                                  \
    RD_FRAGS(ASLOT, BOFF, q);                                \
    VM;                                                      \
    asm volatile("s_waitcnt lgkmcnt(0)" ::: "memory");       \
    __builtin_amdgcn_s_barrier();                            \
    DO_MFMA();                                               \
    __builtin_amdgcn_s_barrier();                            \
  } while (0)

  // ---- prologue: A(0)->E->slot0, A(1)->O; B(0)->o0, B(1)->o1 ----
  int o0 = 0, o1 = 32768, o2 = 65536;
  A_LD(E, 0, 0); A_LD(E, 0, 1); A_LD(E, 0, 2); A_LD(E, 0, 3);
  A_LD(O, 64, 0); A_LD(O, 64, 1); A_LD(O, 64, 2); A_LD(O, 64, 3);
  B_ST(0, 0, 0); B_ST(0, 0, 1); B_ST(0, 0, 2); B_ST(0, 0, 3);
  B_ST(64, 32768, 0); B_ST(64, 32768, 1); B_ST(64, 32768, 2); B_ST(64, 32768, 3);
  asm volatile("s_waitcnt vmcnt(16)" ::: "memory");   // E landed (O+B younger)
  A_WR(E, 0, 0); A_WR(E, 0, 1); A_WR(E, 0, 2); A_WR(E, 0, 3);
  asm volatile("s_waitcnt vmcnt(4)" ::: "memory");    // B(0) landed (B(1) in flight)
  asm volatile("s_waitcnt lgkmcnt(0)" ::: "memory");
  __builtin_amdgcn_s_barrier();

  int kE = 128, kO = 192;  // float k-offsets of tiles staged this body (t+2, t+3)

  // ---- main loop: bodies 0..62 (tiles 0..125), uniform ----
  for (int b = 0; b < 63; ++b) {
    // TH0: compute tile 2b (A slot0, B o0); stage A(2b+2)->E, write A(2b+1)->slot1, B(2b+2)->o2
    PHASE(0, o0, 0, { A_LD(E, kE, 0); A_WR(O, 1, 0); B_ST(kE, o2, 0); }, NOSTG);
    PHASE(0, o0, 1, { A_LD(E, kE, 1); A_WR(O, 1, 1); B_ST(kE, o2, 1); }, NOSTG);
    PHASE(0, o0, 2, { A_LD(E, kE, 2); A_WR(O, 1, 2); B_ST(kE, o2, 2); }, NOSTG);
    PHASE(0, o0, 3, { A_LD(E, kE, 3); A_WR(O, 1, 3); B_ST(kE, o2, 3); }, VM12);
    // TH1: compute tile 2b+1 (A slot1, B o1); stage A(2b+3)->O, write A(2b+2)->slot0, B(2b+3)->o0
    PHASE(32768, o1, 0, { A_LD(O, kO, 0); A_WR(E, 0, 0); B_ST(kO, o0, 0); }, NOSTG);
    PHASE(32768, o1, 1, { A_LD(O, kO, 1); A_WR(E, 0, 1); B_ST(kO, o0, 1); }, NOSTG);
    PHASE(32768, o1, 2, { A_LD(O, kO, 2); A_WR(E, 0, 2); B_ST(kO, o0, 2); }, NOSTG);
    PHASE(32768, o1, 3, { A_LD(O, kO, 3); A_WR(E, 0, 3); B_ST(kO, o0, 3); }, VM12);
    const int n0 = o2, n1 = o0, n2 = o1;
    o0 = n0; o1 = n1; o2 = n2;
    kE += 128; kO += 128;
  }

  // ---- body 63: tiles 126,127 — no staging except final A-write of 127 ----
  PHASE(0, o0, 0, { A_WR(O, 1, 0); }, NOSTG);
  PHASE(0, o0, 1, { A_WR(O, 1, 1); }, NOSTG);
  PHASE(0, o0, 2, { A_WR(O, 1, 2); }, NOSTG);
  PHASE(0, o0, 3, { A_WR(O, 1, 3); }, VM0);
  PHASE(32768, o1, 0, NOSTG, NOSTG);
  PHASE(32768, o1, 1, NOSTG, NOSTG);
  PHASE(32768, o1, 2, NOSTG, NOSTG);
  PHASE(32768, o1, 3, NOSTG, NOSTG);

#undef PHASE
#undef DO_MFMA
#undef RD_FRAGS
#undef B_ST
#undef A_WR
#undef A_LD

  // ---- epilogue: bias + relu; LDS round-trip per n-half for coalesced stores ----
  unsigned short* S16 = (unsigned short*)smem;  // [256][136] bf16 (LAYER0)
  float* S32 = (float*)smem;                    // [256][128] f32  (LAYER1)

#define EPI(AM, BN, ACC) do {                                               \
    const int col = (wave & 1) * 64 + (BN) * 32 + l31;                      \
    const float bvv = bias[col];                                            \
    _Pragma("unroll") for (int r = 0; r < 16; ++r) {                        \
      const int row = wm + (AM) * 32 + (r & 3) + 8 * (r >> 2) + 4 * hk;     \
      float v = ACC[r] + bvv;                                               \
      v = fmaxf(v, 0.f);                                                    \
      if (LAYER == 0) S16[row * 136 + col] = f2bf(v);                       \
      else            S32[row * 128 + col] = v;                             \
    } } while (0)

#pragma unroll
  for (int h = 0; h < 2; ++h) {
    if (((wave >> 1) & 1) == h) {
      EPI(0, 0, c00); EPI(0, 1, c01);
      EPI(1, 0, c10); EPI(1, 1, c11);
      EPI(2, 0, c20); EPI(2, 1, c21);
      EPI(3, 0, c30); EPI(3, 1, c31);
    }
    __syncthreads();
    const int batch = nb * 2 + h;
    const int row = t >> 1, seg = (t & 1) * 64;
    if (LAYER == 0) {
      unsigned short* Dst = (unsigned short*)a.Dst;
      const uint4* src = (const uint4*)&S16[row * 136 + seg];
      uint4* dst = (uint4*)(Dst + ((size_t)(br * 4 + batch) * 8192 + mbase + row) * 128 + seg);
#pragma unroll
      for (int i = 0; i < 8; ++i) dst[i] = src[i];
    } else {
      float* Dst = (float*)a.Dst;
      const float4* src = (const float4*)&S32[row * 128 + seg];
      float4* dst = (float4*)(Dst + ((size_t)(br * 4 + batch) * 8192 + mbase + row) * 128 + seg);
#pragma unroll
      for (int i = 0; i < 16; ++i) dst[i] = src[i];
    }
    __syncthreads();
  }
#undef EPI
}

// ---------------------------------------------------------------- launch
extern "C" void kernel_launch(void* const* d_in, const int* in_sizes, int n_in,
                              void* d_out, int out_size, void* d_ws, size_t ws_size,
                              hipStream_t stream) {
  const float* x = (const float*)d_in[0];
  unsigned short* Z   = (unsigned short*)d_ws;               // [4][512][8192] bf16 (32 MiB)
  unsigned short* H1m = Z + (size_t)4 * 512 * 8192;          // [4][4][8192][128] bf16 (32 MiB)
  unsigned short* WT  = H1m + (size_t)4 * 4 * 8192 * 128;    // [8][128][128] bf16 (256 KiB)
  float* out = (float*)d_out;

  static int attr_done = 0;
  if (!attr_done) {
    hipFuncSetAttribute((const void*)big_gemm<0>, hipFuncAttributeMaxDynamicSharedMemorySize, 163840);
    hipFuncSetAttribute((const void*)big_gemm<1>, hipFuncAttributeMaxDynamicSharedMemorySize, 163840);
    attr_done = 1;
  }

  WPtrs wp;
  for (int b = 0; b < 4; ++b) {
    wp.w[b * 2 + 0] = (const float*)d_in[5 + b * 4 + 0];
    wp.w[b * 2 + 1] = (const float*)d_in[5 + b * 4 + 2];
  }
  prep_w<<<8, 256, 0, stream>>>(wp, WT);

  BigArgs a0, a1;
  for (int b = 0; b < 4; ++b) {
    a0.L[b] = (const float*)d_in[1 + b];
    a1.L[b] = (const float*)d_in[1 + b];
    a0.bias[b] = (const float*)d_in[6 + b * 4];
    a1.bias[b] = (const float*)d_in[8 + b * 4];
  }
  a0.Z = Z; a0.Dst = (void*)H1m;
  a1.Z = Z; a1.Dst = (void*)out;

  small_gemm<1><<<dim3(256, 4), 256, 0, stream>>>(x, nullptr, WT, Z);
  big_gemm<0><<<256, 512, 163840, stream>>>(a0);
  small_gemm<0><<<dim3(256, 4), 256, 0, stream>>>(nullptr, H1m, WT, Z);
  big_gemm<1><<<256, 512, 163840, stream>>>(a1);
}

// Round 8
// 1008.427 us; speedup vs baseline: 1.7609x; 1.7609x over previous
//
#include <hip/hip_runtime.h>
#include <stdint.h>

// GCN multi-branch, round 8 (= round 7 + LAYER1 epilogue LDS-overflow fix).
// relu((L@x)@W+b) == relu(L@(x@W)+b): small input-side W-GEMMs + big L-GEMMs.
// big: 256x256 tile, 8 waves, 32x32x16 MFMA, BK=32, 64B-row LDS, swizzle c^((row>>1)&3),
// per-tile vmcnt(12) pacing (preserves inter-block L2 sharing), 3-tile flight:
// B 4-slot gl_lds ring + A 3-deep reg sets. LAYER1 epilogue now 4x 64KB passes.

typedef short bf16x8 __attribute__((ext_vector_type(8)));
typedef float f32x4  __attribute__((ext_vector_type(4)));
typedef float f32x16 __attribute__((ext_vector_type(16)));

static __device__ __forceinline__ unsigned short f2bf(float f) {
  __bf16 h = (__bf16)f;
  return __builtin_bit_cast(unsigned short, h);
}
static __device__ __forceinline__ unsigned int pack2(float a, float b) {
  return (unsigned int)f2bf(a) | ((unsigned int)f2bf(b) << 16);
}
static __device__ __forceinline__ bf16x8 cvt8(float4 lo, float4 hi) {
  bf16x8 r;
  r[0] = (short)f2bf(lo.x); r[1] = (short)f2bf(lo.y);
  r[2] = (short)f2bf(lo.z); r[3] = (short)f2bf(lo.w);
  r[4] = (short)f2bf(hi.x); r[5] = (short)f2bf(hi.y);
  r[6] = (short)f2bf(hi.z); r[7] = (short)f2bf(hi.w);
  return r;
}

#define GLOAD16(g, l)                                                                  \
  __builtin_amdgcn_global_load_lds((const __attribute__((address_space(1))) void*)(g), \
                                   (__attribute__((address_space(3))) void*)(l), 16, 0, 0)

// ---------------------------------------------------------------- prep: W[fi][fo] -> WT bf16 [fo][fi]
struct WPtrs { const float* w[8]; };
__global__ __launch_bounds__(256)
void prep_w(WPtrs p, unsigned short* __restrict__ wt) {
  const int s = blockIdx.x;
  const float* W = p.w[s];
  unsigned short* dst = wt + s * 16384;
  for (int i = threadIdx.x; i < 16384; i += 256) {
    const int fi = i >> 7, fo = i & 127;
    dst[fo * 128 + fi] = f2bf(W[i]);
  }
}

// ---------------------------------------------------------------- small GEMM: Z = A @ W  (K=128)
template <int AFP32>
__global__ __launch_bounds__(256)
void small_gemm(const float* __restrict__ x, const unsigned short* __restrict__ H1m,
                const unsigned short* __restrict__ WT, unsigned short* __restrict__ Z) {
  __shared__ unsigned short Sa[128 * 136];

  const int t = threadIdx.x, lane = t & 63, wave = t >> 6;
  const int l15 = lane & 15, lk = (lane >> 4) * 8;
  const int wm = (wave >> 1) * 64, wn = (wave & 1) * 64;
  const int mt = blockIdx.x, br = blockIdx.y;
  const int batch = mt >> 6, node0 = (mt & 63) * 128;

  {
    const int row = t >> 1, seg = (t & 1) * 64;
    if (AFP32) {
      const float4* src = (const float4*)(x + ((size_t)batch * 8192 + node0 + row) * 128 + seg);
      uint4* dst = (uint4*)&Sa[row * 136 + seg];
#pragma unroll
      for (int i = 0; i < 8; ++i) {
        float4 a = src[i * 2], b = src[i * 2 + 1];
        uint4 v;
        v.x = pack2(a.x, a.y); v.y = pack2(a.z, a.w);
        v.z = pack2(b.x, b.y); v.w = pack2(b.z, b.w);
        dst[i] = v;
      }
    } else {
      const uint4* src = (const uint4*)(H1m + ((size_t)(br * 4 + batch) * 8192 + node0 + row) * 128 + seg);
      uint4* dst = (uint4*)&Sa[row * 136 + seg];
#pragma unroll
      for (int i = 0; i < 8; ++i) dst[i] = src[i];
    }
  }
  __syncthreads();

  const unsigned short* WTb = WT + (size_t)(2 * br + (AFP32 ? 0 : 1)) * 16384;
  f32x4 acc[4][4];
#pragma unroll
  for (int i = 0; i < 4; ++i)
#pragma unroll
    for (int j = 0; j < 4; ++j) acc[i][j] = f32x4{0.f, 0.f, 0.f, 0.f};

#pragma unroll
  for (int kk = 0; kk < 4; ++kk) {
    bf16x8 av[4], wv[4];
#pragma unroll
    for (int mi = 0; mi < 4; ++mi)
      av[mi] = *(const bf16x8*)&Sa[(wm + mi * 16 + l15) * 136 + kk * 32 + lk];
#pragma unroll
    for (int ni = 0; ni < 4; ++ni)
      wv[ni] = *(const bf16x8*)&WTb[(wn + ni * 16 + l15) * 128 + kk * 32 + lk];
#pragma unroll
    for (int mi = 0; mi < 4; ++mi)
#pragma unroll
      for (int ni = 0; ni < 4; ++ni)
        acc[mi][ni] = __builtin_amdgcn_mfma_f32_16x16x32_bf16(av[mi], wv[ni], acc[mi][ni], 0, 0, 0);
  }

#pragma unroll
  for (int mi = 0; mi < 4; ++mi) {
#pragma unroll
    for (int ni = 0; ni < 4; ++ni) {
      const int row0 = wm + mi * 16 + (lane >> 4) * 4;
      const int col  = wn + ni * 16 + l15;
      uint2 pv;
      pv.x = pack2(acc[mi][ni][0], acc[mi][ni][1]);
      pv.y = pack2(acc[mi][ni][2], acc[mi][ni][3]);
      *(uint2*)(Z + ((size_t)br * 512 + batch * 128 + col) * 8192 + node0 + row0) = pv;
    }
  }
}

// ---------------------------------------------------------------- big GEMM: Dst = relu(L @ Z^T + b)
// LDS: A dbuf 2x16KB @0; B 4-slot ring 4x16KB @32768. 64B rows, swizzle c^((row>>1)&3).
struct BigArgs {
  const float* L[4];
  const float* bias[4];
  const unsigned short* Z;  // [br][512][8192] bf16 n-major
  void* Dst;                // LAYER0: H1 bf16 m-major; LAYER1: out fp32
};

template <int LAYER>
__global__ __launch_bounds__(512, 2)
void big_gemm(BigArgs a) {
  extern __shared__ char smem[];

  const int t = threadIdx.x, lane = t & 63, wave = t >> 6;
  const int l31 = lane & 31, hk = lane >> 5;
  const int wm = (wave >> 2) * 128, wn = (wave & 3) * 64;

  const int bid = blockIdx.x;
  const int work = (bid & 7) * 32 + (bid >> 3);   // XCD-chunked, bijective (256 % 8 == 0)
  const int nb = work & 1, mt = (work >> 1) & 31, br = work >> 6;
  const int mbase = mt * 256;

  const float* A = a.L[br];
  const float* bias = a.bias[br];
  const unsigned short* Zb = a.Z + (size_t)br * (512 * 8192);

  // A staging: thread -> row t>>1 (0..255), k-half ah; 4 float4 loads = 16 floats
  const int arow = t >> 1, ah = t & 1;
  const float* aG = A + (size_t)(mbase + arow) * 8192 + ah * 16;
  const int c0 = 2 * ah, akey = (arow >> 1) & 3;
  char* aRowL = smem + arow * 64;  // + buf*16384 + chunk'*16
  // B staging via gl_lds, pre-swizzled source: row = wave*32+j*16+(lane>>2)
  const unsigned short* bG = Zb + (size_t)(nb * 256 + wave * 32 + (lane >> 2)) * 8192
                                + ((lane & 3) ^ ((lane >> 3) & 3)) * 8;
  char* bWave = smem + 32768 + wave * 2048;  // + slot*16384 + j*1024

  // fragment reads: row key reduces to (l31>>1)&3 for both operands
  const int aBase = (wm + l31) * 64;
  const int bBase = (wn + l31) * 64;
  const int key4 = (l31 >> 1) & 3;

  f32x16 c00{}, c01{}, c10{}, c11{}, c20{}, c21{}, c30{}, c31{};
  float4 s0[4], s1[4], s2[4];
  bf16x8 av0, av1, av2, av3, bv0, bv1;

#define GLB(T_) do {                                                   \
    const unsigned short* _bp = bG + (size_t)(T_) * 32;                \
    char* _bl = bWave + ((T_) & 3) * 16384;                            \
    GLOAD16(_bp, _bl);                                                 \
    GLOAD16(_bp + 16 * 8192, _bl + 1024); } while (0)

#define LOADA(T_, R) do {                                              \
    const float* _ap = aG + (size_t)(T_) * 32;                         \
    R[0] = *(const float4*)(_ap);                                      \
    R[1] = *(const float4*)(_ap + 4);                                  \
    R[2] = *(const float4*)(_ap + 8);                                  \
    R[3] = *(const float4*)(_ap + 12); } while (0)

#define WRITEA(T_, R) do {                                             \
    char* _al = aRowL + (((T_) & 1)) * 16384;                          \
    *(bf16x8*)(_al + ((c0 ^ akey) * 16))       = cvt8(R[0], R[1]);     \
    *(bf16x8*)(_al + (((c0 + 1) ^ akey) * 16)) = cvt8(R[2], R[3]); } while (0)

#define RD(ab_, bb_, s_) do {                                          \
    const int _ch = ((2 * (s_) + hk) ^ key4) * 16;                     \
    av0 = *(const bf16x8*)((ab_) + aBase + _ch);                       \
    av1 = *(const bf16x8*)((ab_) + aBase + 2048 + _ch);                \
    av2 = *(const bf16x8*)((ab_) + aBase + 4096 + _ch);                \
    av3 = *(const bf16x8*)((ab_) + aBase + 6144 + _ch);                \
    bv0 = *(const bf16x8*)((bb_) + bBase + _ch);                       \
    bv1 = *(const bf16x8*)((bb_) + bBase + 2048 + _ch); } while (0)

#define DO_MFMA() do {                                                       \
    __builtin_amdgcn_s_setprio(1);                                           \
    c00 = __builtin_amdgcn_mfma_f32_32x32x16_bf16(av0, bv0, c00, 0, 0, 0);   \
    c01 = __builtin_amdgcn_mfma_f32_32x32x16_bf16(av0, bv1, c01, 0, 0, 0);   \
    c10 = __builtin_amdgcn_mfma_f32_32x32x16_bf16(av1, bv0, c10, 0, 0, 0);   \
    c11 = __builtin_amdgcn_mfma_f32_32x32x16_bf16(av1, bv1, c11, 0, 0, 0);   \
    c20 = __builtin_amdgcn_mfma_f32_32x32x16_bf16(av2, bv0, c20, 0, 0, 0);   \
    c21 = __builtin_amdgcn_mfma_f32_32x32x16_bf16(av2, bv1, c21, 0, 0, 0);   \
    c30 = __builtin_amdgcn_mfma_f32_32x32x16_bf16(av3, bv0, c30, 0, 0, 0);   \
    c31 = __builtin_amdgcn_mfma_f32_32x32x16_bf16(av3, bv1, c31, 0, 0, 0);   \
    __builtin_amdgcn_s_setprio(0); } while (0)

  // ITER T: vmcnt at top forces B(T) (issued T-3) into LDS; one barrier/tile;
  // stage group T+3 (2 gl_lds + 4 reg loads = 6 VMEM/thread); compute 2 k-steps;
  // WRITEA(T+1) mid-tile (compiler inserts the reg-dep vmcnt, which also lands B(T+1)).
#define ITER(T_, SLOAD, SWRITE, VMSTR, DO_STAGE, DO_WRITE) do {        \
    asm volatile("s_waitcnt " VMSTR ::: "memory");                     \
    asm volatile("s_waitcnt lgkmcnt(0)" ::: "memory");                 \
    __builtin_amdgcn_s_barrier();                                      \
    if (DO_STAGE) { GLB((T_) + 3); LOADA((T_) + 3, SLOAD); }           \
    const char* _ab = smem + ((T_) & 1) * 16384;                       \
    const char* _bb = smem + 32768 + ((T_) & 3) * 16384;               \
    RD(_ab, _bb, 0);                                                   \
    DO_MFMA();                                                         \
    if (DO_WRITE) WRITEA((T_) + 1, SWRITE);                            \
    RD(_ab, _bb, 1);                                                   \
    DO_MFMA();                                                         \
  } while (0)

  // ---- prologue: groups 0,1,2 in flight; A(0) -> LDS buf0 ----
  GLB(0); LOADA(0, s0);
  GLB(1); LOADA(1, s1);
  GLB(2); LOADA(2, s2);
  WRITEA(0, s0);  // compiler waits vmcnt(12): forces GLB(0)+LOADA(0) -> B(0),A(0) ready

  // ---- main loop: tiles 0..251 (3-phase set rotation), then 252..255 tail ----
  for (int T = 0; T < 252; T += 3) {
    ITER(T,     s0, s1, "vmcnt(12)", 1, 1);
    ITER(T + 1, s1, s2, "vmcnt(12)", 1, 1);
    ITER(T + 2, s2, s0, "vmcnt(12)", 1, 1);
  }
  ITER(252, s0, s1, "vmcnt(12)", 1, 1);
  ITER(253, s0, s2, "vmcnt(12)", 0, 1);
  ITER(254, s0, s0, "vmcnt(6)",  0, 1);
  ITER(255, s0, s0, "vmcnt(0)",  0, 0);

#undef ITER
#undef DO_MFMA
#undef RD
#undef WRITEA
#undef LOADA
#undef GLB

  // ---- epilogue: bias + relu; LDS round-trip for coalesced stores ----
  __syncthreads();

  if (LAYER == 0) {
    // bf16 H1: [256][136] = 69632 B <= 96KB, 2 passes over batch halves
    unsigned short* S16 = (unsigned short*)smem;
#define EPI16(AM, BN, ACC) do {                                             \
    const int col = (wave & 1) * 64 + (BN) * 32 + l31;                      \
    const float bvv = bias[col];                                            \
    _Pragma("unroll") for (int r = 0; r < 16; ++r) {                        \
      const int row = wm + (AM) * 32 + (r & 3) + 8 * (r >> 2) + 4 * hk;     \
      S16[row * 136 + col] = f2bf(fmaxf(ACC[r] + bvv, 0.f));                \
    } } while (0)
#pragma unroll
    for (int h = 0; h < 2; ++h) {
      if (((wave >> 1) & 1) == h) {
        EPI16(0, 0, c00); EPI16(0, 1, c01);
        EPI16(1, 0, c10); EPI16(1, 1, c11);
        EPI16(2, 0, c20); EPI16(2, 1, c21);
        EPI16(3, 0, c30); EPI16(3, 1, c31);
      }
      __syncthreads();
      const int batch = nb * 2 + h;
      const int row = t >> 1, seg = (t & 1) * 64;
      unsigned short* Dst = (unsigned short*)a.Dst;
      const uint4* src = (const uint4*)&S16[row * 136 + seg];
      uint4* dst = (uint4*)(Dst + ((size_t)(br * 4 + batch) * 8192 + mbase + row) * 128 + seg);
#pragma unroll
      for (int i = 0; i < 8; ++i) dst[i] = src[i];
      __syncthreads();
    }
#undef EPI16
  } else {
    // fp32 out: [128][128] f32 = 64KB per pass <= 96KB; 4 passes (batch-half x row-half).
    // (r7 bug: single 256-row pass needed 128KB > 96KB allocation -> OOB garbage.)
    float* S32 = (float*)smem;
#define EPI32(AM, BN, ACC) do {                                             \
    const int col = (wave & 1) * 64 + (BN) * 32 + l31;                      \
    const float bvv = bias[col];                                            \
    _Pragma("unroll") for (int r = 0; r < 16; ++r) {                        \
      const int lrow = (AM) * 32 + (r & 3) + 8 * (r >> 2) + 4 * hk;         \
      S32[lrow * 128 + col] = fmaxf(ACC[r] + bvv, 0.f);                     \
    } } while (0)
#pragma unroll
    for (int h = 0; h < 2; ++h) {
#pragma unroll
      for (int rh = 0; rh < 2; ++rh) {
        if (((wave >> 1) & 1) == h && (wave >> 2) == rh) {
          EPI32(0, 0, c00); EPI32(0, 1, c01);
          EPI32(1, 0, c10); EPI32(1, 1, c11);
          EPI32(2, 0, c20); EPI32(2, 1, c21);
          EPI32(3, 0, c30); EPI32(3, 1, c31);
        }
        __syncthreads();
        const int batch = nb * 2 + h;
        const int row = t >> 2, seg = (t & 3) * 32;
        float* Dst = (float*)a.Dst;
        const float4* src = (const float4*)&S32[row * 128 + seg];
        float4* dst = (float4*)(Dst + ((size_t)(br * 4 + batch) * 8192 + mbase + rh * 128 + row) * 128 + seg);
#pragma unroll
        for (int i = 0; i < 8; ++i) dst[i] = src[i];
        __syncthreads();
      }
    }
#undef EPI32
  }
}

// ---------------------------------------------------------------- launch
extern "C" void kernel_launch(void* const* d_in, const int* in_sizes, int n_in,
                              void* d_out, int out_size, void* d_ws, size_t ws_size,
                              hipStream_t stream) {
  const float* x = (const float*)d_in[0];
  unsigned short* Z   = (unsigned short*)d_ws;               // [4][512][8192] bf16 (32 MiB)
  unsigned short* H1m = Z + (size_t)4 * 512 * 8192;          // [4][4][8192][128] bf16 (32 MiB)
  unsigned short* WT  = H1m + (size_t)4 * 4 * 8192 * 128;    // [8][128][128] bf16 (256 KiB)
  float* out = (float*)d_out;

  static int attr_done = 0;
  if (!attr_done) {
    hipFuncSetAttribute((const void*)big_gemm<0>, hipFuncAttributeMaxDynamicSharedMemorySize, 98304);
    hipFuncSetAttribute((const void*)big_gemm<1>, hipFuncAttributeMaxDynamicSharedMemorySize, 98304);
    attr_done = 1;
  }

  WPtrs wp;
  for (int b = 0; b < 4; ++b) {
    wp.w[b * 2 + 0] = (const float*)d_in[5 + b * 4 + 0];
    wp.w[b * 2 + 1] = (const float*)d_in[5 + b * 4 + 2];
  }
  prep_w<<<8, 256, 0, stream>>>(wp, WT);

  BigArgs a0, a1;
  for (int b = 0; b < 4; ++b) {
    a0.L[b] = (const float*)d_in[1 + b];
    a1.L[b] = (const float*)d_in[1 + b];
    a0.bias[b] = (const float*)d_in[6 + b * 4];
    a1.bias[b] = (const float*)d_in[8 + b * 4];
  }
  a0.Z = Z; a0.Dst = (void*)H1m;
  a1.Z = Z; a1.Dst = (void*)out;

  small_gemm<1><<<dim3(256, 4), 256, 0, stream>>>(x, nullptr, WT, Z);
  big_gemm<0><<<256, 512, 98304, stream>>>(a0);
  small_gemm<0><<<dim3(256, 4), 256, 0, stream>>>(nullptr, H1m, WT, Z);
  big_gemm<1><<<256, 512, 98304, stream>>>(a1);
}

// Round 9
// 934.796 us; speedup vs baseline: 1.8996x; 1.0788x over previous
//
#include <hip/hip_runtime.h>
#include <stdint.h>

// GCN multi-branch, round 9.
// relu((L@x)@W+b) == relu(L@(x@W)+b): small input-side W-GEMMs + big L-GEMMs.
// NEW: L pre-converted once to bf16 in tile-image layout [br][mt][kt][256r][64B,swizzled]
// so big_gemm stages A via pure linear global_load_lds (contiguous 16KB/tile DRAM reads),
// 4-slot A+B LDS rings, one barrier/tile, counted vmcnt(8). Fallback to r8 path if ws small.

typedef short bf16x8 __attribute__((ext_vector_type(8)));
typedef float f32x4  __attribute__((ext_vector_type(4)));
typedef float f32x16 __attribute__((ext_vector_type(16)));

static __device__ __forceinline__ unsigned short f2bf(float f) {
  __bf16 h = (__bf16)f;
  return __builtin_bit_cast(unsigned short, h);
}
static __device__ __forceinline__ unsigned int pack2(float a, float b) {
  return (unsigned int)f2bf(a) | ((unsigned int)f2bf(b) << 16);
}
static __device__ __forceinline__ bf16x8 cvt8(float4 lo, float4 hi) {
  bf16x8 r;
  r[0] = (short)f2bf(lo.x); r[1] = (short)f2bf(lo.y);
  r[2] = (short)f2bf(lo.z); r[3] = (short)f2bf(lo.w);
  r[4] = (short)f2bf(hi.x); r[5] = (short)f2bf(hi.y);
  r[6] = (short)f2bf(hi.z); r[7] = (short)f2bf(hi.w);
  return r;
}

#define GLOAD16(g, l)                                                                  \
  __builtin_amdgcn_global_load_lds((const __attribute__((address_space(1))) void*)(g), \
                                   (__attribute__((address_space(3))) void*)(l), 16, 0, 0)

// ---------------------------------------------------------------- prep: W[fi][fo] -> WT bf16 [fo][fi]
struct WPtrs { const float* w[8]; };
__global__ __launch_bounds__(256)
void prep_w(WPtrs p, unsigned short* __restrict__ wt) {
  const int s = blockIdx.x;
  const float* W = p.w[s];
  unsigned short* dst = wt + s * 16384;
  for (int i = threadIdx.x; i < 16384; i += 256) {
    const int fi = i >> 7, fo = i & 127;
    dst[fo * 128 + fi] = f2bf(W[i]);
  }
}

// ---------------------------------------------------------------- conv: L fp32 -> bf16 tile images
// Lbf layout: [br][mt 32][kt 256] tiles of 16KB = [row 256][chunk16B ^ ((row>>1)&3)].
// Block: 64 rows x 512 k (16 kt). Reads 2KB/row contiguous; writes 4KB slices contiguous.
struct LPtrs { const float* l[4]; };
__global__ __launch_bounds__(256)
void conv_l(LPtrs p, char* __restrict__ lbf) {
  __shared__ char T[65536];  // [ktl 16][rr 64][64B]
  const int t = threadIdx.x, lane = t & 63, wave = t >> 6;
  const int rg = blockIdx.x, kg = blockIdx.y, br = blockIdx.z;
  const float* L = p.l[br];
  const int r0 = rg * 64, k0 = kg * 512;
  const int mt = rg >> 2, rowoff = (rg & 3) * 64, kt0 = kg * 16;
#pragma unroll
  for (int i = 0; i < 16; ++i) {
    const int rr = wave * 16 + i;
    const float* src = L + (size_t)(r0 + rr) * 8192 + k0;
#pragma unroll
    for (int half = 0; half < 2; ++half) {
      float4 v = ((const float4*)src)[half * 64 + lane];   // 1KB/wave-instr contiguous
      const int ktl = half * 8 + (lane >> 3);
      const int ch  = ((lane >> 1) & 3) ^ ((rr >> 1) & 3); // swizzle baked in
      uint2 pv; pv.x = pack2(v.x, v.y); pv.y = pack2(v.z, v.w);
      *(uint2*)(T + ktl * 4096 + rr * 64 + ch * 16 + (lane & 1) * 8) = pv;
    }
  }
  __syncthreads();
  char* dstb = lbf + ((size_t)(br * 32 + mt) * 256 + kt0) * 16384 + rowoff * 64;
#pragma unroll
  for (int ktl = 0; ktl < 16; ++ktl)
    ((uint4*)(dstb + (size_t)ktl * 16384))[t] = ((const uint4*)(T + ktl * 4096))[t];
}

// ---------------------------------------------------------------- small GEMM: Z = A @ W  (K=128)
template <int AFP32>
__global__ __launch_bounds__(256)
void small_gemm(const float* __restrict__ x, const unsigned short* __restrict__ H1m,
                const unsigned short* __restrict__ WT, unsigned short* __restrict__ Z) {
  __shared__ unsigned short Sa[128 * 136];

  const int t = threadIdx.x, lane = t & 63, wave = t >> 6;
  const int l15 = lane & 15, lk = (lane >> 4) * 8;
  const int wm = (wave >> 1) * 64, wn = (wave & 1) * 64;
  const int mt = blockIdx.x, br = blockIdx.y;
  const int batch = mt >> 6, node0 = (mt & 63) * 128;

  {
    const int row = t >> 1, seg = (t & 1) * 64;
    if (AFP32) {
      const float4* src = (const float4*)(x + ((size_t)batch * 8192 + node0 + row) * 128 + seg);
      uint4* dst = (uint4*)&Sa[row * 136 + seg];
#pragma unroll
      for (int i = 0; i < 8; ++i) {
        float4 a = src[i * 2], b = src[i * 2 + 1];
        uint4 v;
        v.x = pack2(a.x, a.y); v.y = pack2(a.z, a.w);
        v.z = pack2(b.x, b.y); v.w = pack2(b.z, b.w);
        dst[i] = v;
      }
    } else {
      const uint4* src = (const uint4*)(H1m + ((size_t)(br * 4 + batch) * 8192 + node0 + row) * 128 + seg);
      uint4* dst = (uint4*)&Sa[row * 136 + seg];
#pragma unroll
      for (int i = 0; i < 8; ++i) dst[i] = src[i];
    }
  }
  __syncthreads();

  const unsigned short* WTb = WT + (size_t)(2 * br + (AFP32 ? 0 : 1)) * 16384;
  f32x4 acc[4][4];
#pragma unroll
  for (int i = 0; i < 4; ++i)
#pragma unroll
    for (int j = 0; j < 4; ++j) acc[i][j] = f32x4{0.f, 0.f, 0.f, 0.f};

#pragma unroll
  for (int kk = 0; kk < 4; ++kk) {
    bf16x8 av[4], wv[4];
#pragma unroll
    for (int mi = 0; mi < 4; ++mi)
      av[mi] = *(const bf16x8*)&Sa[(wm + mi * 16 + l15) * 136 + kk * 32 + lk];
#pragma unroll
    for (int ni = 0; ni < 4; ++ni)
      wv[ni] = *(const bf16x8*)&WTb[(wn + ni * 16 + l15) * 128 + kk * 32 + lk];
#pragma unroll
    for (int mi = 0; mi < 4; ++mi)
#pragma unroll
      for (int ni = 0; ni < 4; ++ni)
        acc[mi][ni] = __builtin_amdgcn_mfma_f32_16x16x32_bf16(av[mi], wv[ni], acc[mi][ni], 0, 0, 0);
  }

#pragma unroll
  for (int mi = 0; mi < 4; ++mi) {
#pragma unroll
    for (int ni = 0; ni < 4; ++ni) {
      const int row0 = wm + mi * 16 + (lane >> 4) * 4;
      const int col  = wn + ni * 16 + l15;
      uint2 pv;
      pv.x = pack2(acc[mi][ni][0], acc[mi][ni][1]);
      pv.y = pack2(acc[mi][ni][2], acc[mi][ni][3]);
      *(uint2*)(Z + ((size_t)br * 512 + batch * 128 + col) * 8192 + node0 + row0) = pv;
    }
  }
}

// ---------------------------------------------------------------- shared epilogue + args
struct BigArgs {
  const float* L[4];
  const float* bias[4];
  const unsigned short* Z;  // [br][512][8192] bf16 n-major
  void* Dst;                // LAYER0: H1 bf16 m-major; LAYER1: out fp32
};

#define DO_MFMA() do {                                                       \
    __builtin_amdgcn_s_setprio(1);                                           \
    c00 = __builtin_amdgcn_mfma_f32_32x32x16_bf16(av0, bv0, c00, 0, 0, 0);   \
    c01 = __builtin_amdgcn_mfma_f32_32x32x16_bf16(av0, bv1, c01, 0, 0, 0);   \
    c10 = __builtin_amdgcn_mfma_f32_32x32x16_bf16(av1, bv0, c10, 0, 0, 0);   \
    c11 = __builtin_amdgcn_mfma_f32_32x32x16_bf16(av1, bv1, c11, 0, 0, 0);   \
    c20 = __builtin_amdgcn_mfma_f32_32x32x16_bf16(av2, bv0, c20, 0, 0, 0);   \
    c21 = __builtin_amdgcn_mfma_f32_32x32x16_bf16(av2, bv1, c21, 0, 0, 0);   \
    c30 = __builtin_amdgcn_mfma_f32_32x32x16_bf16(av3, bv0, c30, 0, 0, 0);   \
    c31 = __builtin_amdgcn_mfma_f32_32x32x16_bf16(av3, bv1, c31, 0, 0, 0);   \
    __builtin_amdgcn_s_setprio(0); } while (0)

#define RD(ab_, bb_, s_) do {                                          \
    const int _ch = ((2 * (s_) + hk) ^ key4) * 16;                     \
    av0 = *(const bf16x8*)((ab_) + aBase + _ch);                       \
    av1 = *(const bf16x8*)((ab_) + aBase + 2048 + _ch);                \
    av2 = *(const bf16x8*)((ab_) + aBase + 4096 + _ch);                \
    av3 = *(const bf16x8*)((ab_) + aBase + 6144 + _ch);                \
    bv0 = *(const bf16x8*)((bb_) + bBase + _ch);                       \
    bv1 = *(const bf16x8*)((bb_) + bBase + 2048 + _ch); } while (0)

// epilogue used by both big variants (smem >= 64KB required)
#define BIG_EPILOGUE()                                                                     \
  __syncthreads();                                                                          \
  if (LAYER == 0) {                                                                         \
    unsigned short* S16 = (unsigned short*)smem;                                            \
    _Pragma("unroll")                                                                       \
    for (int h = 0; h < 2; ++h) {                                                           \
      if (((wave >> 1) & 1) == h) {                                                         \
        EPI16(0, 0, c00); EPI16(0, 1, c01);                                                 \
        EPI16(1, 0, c10); EPI16(1, 1, c11);                                                 \
        EPI16(2, 0, c20); EPI16(2, 1, c21);                                                 \
        EPI16(3, 0, c30); EPI16(3, 1, c31);                                                 \
      }                                                                                     \
      __syncthreads();                                                                      \
      const int batch = nb * 2 + h;                                                         \
      const int row = t >> 1, seg = (t & 1) * 64;                                           \
      unsigned short* Dst = (unsigned short*)a.Dst;                                         \
      const uint4* src = (const uint4*)&S16[row * 136 + seg];                               \
      uint4* dst = (uint4*)(Dst + ((size_t)(br * 4 + batch) * 8192 + mbase + row) * 128 + seg); \
      _Pragma("unroll") for (int i = 0; i < 8; ++i) dst[i] = src[i];                        \
      __syncthreads();                                                                      \
    }                                                                                       \
  } else {                                                                                  \
    float* S32 = (float*)smem;                                                              \
    _Pragma("unroll")                                                                       \
    for (int h = 0; h < 2; ++h) {                                                           \
      _Pragma("unroll")                                                                     \
      for (int rh = 0; rh < 2; ++rh) {                                                      \
        if (((wave >> 1) & 1) == h && (wave >> 2) == rh) {                                  \
          EPI32(0, 0, c00); EPI32(0, 1, c01);                                               \
          EPI32(1, 0, c10); EPI32(1, 1, c11);                                               \
          EPI32(2, 0, c20); EPI32(2, 1, c21);                                               \
          EPI32(3, 0, c30); EPI32(3, 1, c31);                                               \
        }                                                                                   \
        __syncthreads();                                                                    \
        const int batch = nb * 2 + h;                                                       \
        const int row = t >> 2, seg = (t & 3) * 32;                                         \
        float* Dst = (float*)a.Dst;                                                         \
        const float4* src = (const float4*)&S32[row * 128 + seg];                           \
        float4* dst = (float4*)(Dst + ((size_t)(br * 4 + batch) * 8192 + mbase + rh * 128 + row) * 128 + seg); \
        _Pragma("unroll") for (int i = 0; i < 8; ++i) dst[i] = src[i];                      \
        __syncthreads();                                                                    \
      }                                                                                     \
    }                                                                                       \
  }

#define EPI16(AM, BN, ACC) do {                                             \
    const int col = (wave & 1) * 64 + (BN) * 32 + l31;                      \
    const float bvv = bias[col];                                            \
    _Pragma("unroll") for (int r = 0; r < 16; ++r) {                        \
      const int row = wm + (AM) * 32 + (r & 3) + 8 * (r >> 2) + 4 * hk;     \
      S16[row * 136 + col] = f2bf(fmaxf(ACC[r] + bvv, 0.f));                \
    } } while (0)
#define EPI32(AM, BN, ACC) do {                                             \
    const int col = (wave & 1) * 64 + (BN) * 32 + l31;                      \
    const float bvv = bias[col];                                            \
    _Pragma("unroll") for (int r = 0; r < 16; ++r) {                        \
      const int lrow = (AM) * 32 + (r & 3) + 8 * (r >> 2) + 4 * hk;         \
      S32[lrow * 128 + col] = fmaxf(ACC[r] + bvv, 0.f);                     \
    } } while (0)

// ---------------------------------------------------------------- big GEMM (pre-converted A)
// LDS: A ring 4x16KB @0, B ring 4x16KB @65536. One barrier/tile, vmcnt(8) pacing.
template <int LAYER>
__global__ __launch_bounds__(512)
void big_gemm_pc(BigArgs a, const char* __restrict__ Lbf) {
  extern __shared__ char smem[];

  const int t = threadIdx.x, lane = t & 63, wave = t >> 6;
  const int l31 = lane & 31, hk = lane >> 5;
  const int wm = (wave >> 2) * 128, wn = (wave & 3) * 64;

  const int bid = blockIdx.x;
  const int work = (bid & 7) * 32 + (bid >> 3);   // XCD-chunked, bijective
  const int nb = work & 1, mt = (work >> 1) & 31, br = work >> 6;
  const int mbase = mt * 256;

  const float* bias = a.bias[br];
  const unsigned short* Zb = a.Z + (size_t)br * (512 * 8192);

  // A: linear copy of pre-swizzled tile images
  const char* aTiles = Lbf + ((size_t)(br * 32 + mt) * 256) * 16384;
  // B: pre-swizzled source (r8-proven)
  const unsigned short* bG = Zb + (size_t)(nb * 256 + wave * 32 + (lane >> 2)) * 8192
                                + ((lane & 3) ^ ((lane >> 3) & 3)) * 8;

  const int aBase = (wm + l31) * 64;
  const int bBase = (wn + l31) * 64;
  const int key4 = (l31 >> 1) & 3;

  f32x16 c00{}, c01{}, c10{}, c11{}, c20{}, c21{}, c30{}, c31{};
  bf16x8 av0, av1, av2, av3, bv0, bv1;

#define STG(T_) do {                                                          \
    const char* _as = aTiles + (size_t)(T_) * 16384 + wave * 2048 + lane * 16;\
    char* _ad = smem + ((T_) & 3) * 16384 + wave * 2048;                      \
    GLOAD16(_as, _ad);                                                        \
    GLOAD16(_as + 1024, _ad + 1024);                                          \
    const unsigned short* _bp = bG + (size_t)(T_) * 32;                       \
    char* _bl = smem + 65536 + ((T_) & 3) * 16384 + wave * 2048;              \
    GLOAD16(_bp, _bl);                                                        \
    GLOAD16(_bp + 16 * 8192, _bl + 1024); } while (0)

#define ITER(T_, VMSTR, DO_STG) do {                                          \
    asm volatile("s_waitcnt " VMSTR ::: "memory");                            \
    __builtin_amdgcn_s_barrier();                                             \
    if (DO_STG) STG((T_) + 3);                                                \
    const char* _ab = smem + ((T_) & 3) * 16384;                              \
    const char* _bb = smem + 65536 + ((T_) & 3) * 16384;                      \
    RD(_ab, _bb, 0);                                                          \
    DO_MFMA();                                                                \
    RD(_ab, _bb, 1);                                                          \
    DO_MFMA();                                                                \
  } while (0)

  // prologue: groups 0,1,2 in flight (12 VMEM/thread)
  STG(0); STG(1); STG(2);

  for (int T = 0; T < 252; T += 4) {
    ITER(T,     "vmcnt(8)", 1);
    ITER(T + 1, "vmcnt(8)", 1);
    ITER(T + 2, "vmcnt(8)", 1);
    ITER(T + 3, "vmcnt(8)", 1);
  }
  ITER(252, "vmcnt(8)", 1);   // stages group 255
  ITER(253, "vmcnt(8)", 0);
  ITER(254, "vmcnt(4)", 0);
  ITER(255, "vmcnt(0)", 0);
#undef ITER
#undef STG

  BIG_EPILOGUE()
}

// ---------------------------------------------------------------- big GEMM (r8 fallback, reg-staged A)
template <int LAYER>
__global__ __launch_bounds__(512, 2)
void big_gemm_rs(BigArgs a) {
  extern __shared__ char smem[];

  const int t = threadIdx.x, lane = t & 63, wave = t >> 6;
  const int l31 = lane & 31, hk = lane >> 5;
  const int wm = (wave >> 2) * 128, wn = (wave & 3) * 64;

  const int bid = blockIdx.x;
  const int work = (bid & 7) * 32 + (bid >> 3);
  const int nb = work & 1, mt = (work >> 1) & 31, br = work >> 6;
  const int mbase = mt * 256;

  const float* A = a.L[br];
  const float* bias = a.bias[br];
  const unsigned short* Zb = a.Z + (size_t)br * (512 * 8192);

  const int arow = t >> 1, ah = t & 1;
  const float* aG = A + (size_t)(mbase + arow) * 8192 + ah * 16;
  const int c0 = 2 * ah, akey = (arow >> 1) & 3;
  char* aRowL = smem + arow * 64;
  const unsigned short* bG = Zb + (size_t)(nb * 256 + wave * 32 + (lane >> 2)) * 8192
                                + ((lane & 3) ^ ((lane >> 3) & 3)) * 8;
  char* bWave = smem + 32768 + wave * 2048;

  const int aBase = (wm + l31) * 64;
  const int bBase = (wn + l31) * 64;
  const int key4 = (l31 >> 1) & 3;

  f32x16 c00{}, c01{}, c10{}, c11{}, c20{}, c21{}, c30{}, c31{};
  float4 s0[4], s1[4], s2[4];
  bf16x8 av0, av1, av2, av3, bv0, bv1;

#define GLB(T_) do {                                                   \
    const unsigned short* _bp = bG + (size_t)(T_) * 32;                \
    char* _bl = bWave + ((T_) & 3) * 16384;                            \
    GLOAD16(_bp, _bl);                                                 \
    GLOAD16(_bp + 16 * 8192, _bl + 1024); } while (0)
#define LOADA(T_, R) do {                                              \
    const float* _ap = aG + (size_t)(T_) * 32;                         \
    R[0] = *(const float4*)(_ap);                                      \
    R[1] = *(const float4*)(_ap + 4);                                  \
    R[2] = *(const float4*)(_ap + 8);                                  \
    R[3] = *(const float4*)(_ap + 12); } while (0)
#define WRITEA(T_, R) do {                                             \
    char* _al = aRowL + (((T_) & 1)) * 16384;                          \
    *(bf16x8*)(_al + ((c0 ^ akey) * 16))       = cvt8(R[0], R[1]);     \
    *(bf16x8*)(_al + (((c0 + 1) ^ akey) * 16)) = cvt8(R[2], R[3]); } while (0)
#define ITER(T_, SLOAD, SWRITE, VMSTR, DO_STAGE, DO_WRITE) do {        \
    asm volatile("s_waitcnt " VMSTR ::: "memory");                     \
    asm volatile("s_waitcnt lgkmcnt(0)" ::: "memory");                 \
    __builtin_amdgcn_s_barrier();                                      \
    if (DO_STAGE) { GLB((T_) + 3); LOADA((T_) + 3, SLOAD); }           \
    const char* _ab = smem + ((T_) & 1) * 16384;                       \
    const char* _bb = smem + 32768 + ((T_) & 3) * 16384;               \
    RD(_ab, _bb, 0);                                                   \
    DO_MFMA();                                                         \
    if (DO_WRITE) WRITEA((T_) + 1, SWRITE);                            \
    RD(_ab, _bb, 1);                                                   \
    DO_MFMA();                                                         \
  } while (0)

  GLB(0); LOADA(0, s0);
  GLB(1); LOADA(1, s1);
  GLB(2); LOADA(2, s2);
  WRITEA(0, s0);

  for (int T = 0; T < 252; T += 3) {
    ITER(T,     s0, s1, "vmcnt(12)", 1, 1);
    ITER(T + 1, s1, s2, "vmcnt(12)", 1, 1);
    ITER(T + 2, s2, s0, "vmcnt(12)", 1, 1);
  }
  ITER(252, s0, s1, "vmcnt(12)", 1, 1);
  ITER(253, s0, s2, "vmcnt(12)", 0, 1);
  ITER(254, s0, s0, "vmcnt(6)",  0, 1);
  ITER(255, s0, s0, "vmcnt(0)",  0, 0);
#undef ITER
#undef WRITEA
#undef LOADA
#undef GLB

  BIG_EPILOGUE()
}

// ---------------------------------------------------------------- launch
extern "C" void kernel_launch(void* const* d_in, const int* in_sizes, int n_in,
                              void* d_out, int out_size, void* d_ws, size_t ws_size,
                              hipStream_t stream) {
  const float* x = (const float*)d_in[0];
  unsigned short* Z   = (unsigned short*)d_ws;               // [4][512][8192] bf16 (32 MiB)
  unsigned short* H1m = Z + (size_t)4 * 512 * 8192;          // [4][4][8192][128] bf16 (32 MiB)
  unsigned short* WT  = H1m + (size_t)4 * 4 * 8192 * 128;    // [8][128][128] bf16 (256 KiB)
  char* Lbf = (char*)(WT + 8 * 16384);                       // [4][32][256] 16KB tiles (512 MiB)
  float* out = (float*)d_out;

  const size_t NEED_PC = (size_t)33554432 + 33554432 + 262144 + 536870912;  // 604,241,920
  const bool use_pc = ws_size >= NEED_PC;

  static int attr_done = 0;
  if (!attr_done) {
    hipFuncSetAttribute((const void*)big_gemm_pc<0>, hipFuncAttributeMaxDynamicSharedMemorySize, 131072);
    hipFuncSetAttribute((const void*)big_gemm_pc<1>, hipFuncAttributeMaxDynamicSharedMemorySize, 131072);
    hipFuncSetAttribute((const void*)big_gemm_rs<0>, hipFuncAttributeMaxDynamicSharedMemorySize, 98304);
    hipFuncSetAttribute((const void*)big_gemm_rs<1>, hipFuncAttributeMaxDynamicSharedMemorySize, 98304);
    attr_done = 1;
  }

  WPtrs wp;
  for (int b = 0; b < 4; ++b) {
    wp.w[b * 2 + 0] = (const float*)d_in[5 + b * 4 + 0];
    wp.w[b * 2 + 1] = (const float*)d_in[5 + b * 4 + 2];
  }
  prep_w<<<8, 256, 0, stream>>>(wp, WT);

  BigArgs a0, a1;
  for (int b = 0; b < 4; ++b) {
    a0.L[b] = (const float*)d_in[1 + b];
    a1.L[b] = (const float*)d_in[1 + b];
    a0.bias[b] = (const float*)d_in[6 + b * 4];
    a1.bias[b] = (const float*)d_in[8 + b * 4];
  }
  a0.Z = Z; a0.Dst = (void*)H1m;
  a1.Z = Z; a1.Dst = (void*)out;

  if (use_pc) {
    LPtrs lp;
    for (int b = 0; b < 4; ++b) lp.l[b] = (const float*)d_in[1 + b];
    conv_l<<<dim3(128, 16, 4), 256, 0, stream>>>(lp, Lbf);
    small_gemm<1><<<dim3(256, 4), 256, 0, stream>>>(x, nullptr, WT, Z);
    big_gemm_pc<0><<<256, 512, 131072, stream>>>(a0, Lbf);
    small_gemm<0><<<dim3(256, 4), 256, 0, stream>>>(nullptr, H1m, WT, Z);
    big_gemm_pc<1><<<256, 512, 131072, stream>>>(a1, Lbf);
  } else {
    small_gemm<1><<<dim3(256, 4), 256, 0, stream>>>(x, nullptr, WT, Z);
    big_gemm_rs<0><<<256, 512, 98304, stream>>>(a0);
    small_gemm<0><<<dim3(256, 4), 256, 0, stream>>>(nullptr, H1m, WT, Z);
    big_gemm_rs<1><<<256, 512, 98304, stream>>>(a1);
  }
}

// Round 11
// 924.641 us; speedup vs baseline: 1.9204x; 1.0110x over previous
//
#include <hip/hip_runtime.h>
#include <stdint.h>

// GCN multi-branch, round 11 (= round 10 with nontemporal vector-type compile fix).
// relu((L@x)@W+b) == relu(L@(x@W)+b): small input-side W-GEMMs + big L-GEMMs.
// L pre-converted once (conv_l) to bf16 tile images [br][mt][kt][256r][64B swizzled];
// big_gemm_pc stages A+B via linear global_load_lds, 4-slot rings, 1 barrier/tile,
// vmcnt(8) pacing, 2-set k-step register pipeline. conv_l: 32KB LDS, 4 blocks/CU,
// nontemporal streaming. Fallback to r8 reg-staged path if ws too small.

typedef short bf16x8 __attribute__((ext_vector_type(8)));
typedef float f32x4  __attribute__((ext_vector_type(4)));
typedef unsigned int u32x4 __attribute__((ext_vector_type(4)));
typedef float f32x16 __attribute__((ext_vector_type(16)));

static __device__ __forceinline__ unsigned short f2bf(float f) {
  __bf16 h = (__bf16)f;
  return __builtin_bit_cast(unsigned short, h);
}
static __device__ __forceinline__ unsigned int pack2(float a, float b) {
  return (unsigned int)f2bf(a) | ((unsigned int)f2bf(b) << 16);
}
static __device__ __forceinline__ bf16x8 cvt8(float4 lo, float4 hi) {
  bf16x8 r;
  r[0] = (short)f2bf(lo.x); r[1] = (short)f2bf(lo.y);
  r[2] = (short)f2bf(lo.z); r[3] = (short)f2bf(lo.w);
  r[4] = (short)f2bf(hi.x); r[5] = (short)f2bf(hi.y);
  r[6] = (short)f2bf(hi.z); r[7] = (short)f2bf(hi.w);
  return r;
}

#define GLOAD16(g, l)                                                                  \
  __builtin_amdgcn_global_load_lds((const __attribute__((address_space(1))) void*)(g), \
                                   (__attribute__((address_space(3))) void*)(l), 16, 0, 0)

// ---------------------------------------------------------------- prep: W[fi][fo] -> WT bf16 [fo][fi]
struct WPtrs { const float* w[8]; };
__global__ __launch_bounds__(256)
void prep_w(WPtrs p, unsigned short* __restrict__ wt) {
  const int s = blockIdx.x;
  const float* W = p.w[s];
  unsigned short* dst = wt + s * 16384;
  for (int i = threadIdx.x; i < 16384; i += 256) {
    const int fi = i >> 7, fo = i & 127;
    dst[fo * 128 + fi] = f2bf(W[i]);
  }
}

// ---------------------------------------------------------------- conv: L fp32 -> bf16 tile images
// Lbf layout: [br][mt 32][kt 256] tiles of 16KB = [row 256][chunk16B ^ ((row>>1)&3)].
// Block = 64 rows x 256 k (8 ktl), 32KB LDS -> 4 blocks/CU; nontemporal streaming.
struct LPtrs { const float* l[4]; };
__global__ __launch_bounds__(256)
void conv_l(LPtrs p, char* __restrict__ lbf) {
  __shared__ char T[32768];  // [ktl 8][rr 64][64B]
  const int t = threadIdx.x, lane = t & 63, wave = t >> 6;
  const int rg = blockIdx.x, kg = blockIdx.y, br = blockIdx.z;
  const float* L = p.l[br];
  const int r0 = rg * 64, k0 = kg * 256;
  const int mt = rg >> 2, rowoff = (rg & 3) * 64, kt0 = kg * 8;
#pragma unroll
  for (int i = 0; i < 16; ++i) {
    const int rr = wave * 16 + i;
    const f32x4* src = (const f32x4*)(L + (size_t)(r0 + rr) * 8192 + k0);
    f32x4 v = __builtin_nontemporal_load(src + lane);    // 1KB/wave-instr contiguous
    const int ktl = lane >> 3;
    const int ch  = ((lane >> 1) & 3) ^ ((rr >> 1) & 3); // swizzle baked in
    uint2 pv; pv.x = pack2(v[0], v[1]); pv.y = pack2(v[2], v[3]);
    *(uint2*)(T + ktl * 4096 + rr * 64 + ch * 16 + (lane & 1) * 8) = pv;
  }
  __syncthreads();
  char* dstb = lbf + ((size_t)(br * 32 + mt) * 256 + kt0) * 16384 + rowoff * 64;
#pragma unroll
  for (int ktl = 0; ktl < 8; ++ktl) {
    u32x4 v = ((const u32x4*)(T + ktl * 4096))[t];
    __builtin_nontemporal_store(v, (u32x4*)(dstb + (size_t)ktl * 16384) + t);
  }
}

// ---------------------------------------------------------------- small GEMM: Z = A @ W  (K=128)
template <int AFP32>
__global__ __launch_bounds__(256)
void small_gemm(const float* __restrict__ x, const unsigned short* __restrict__ H1m,
                const unsigned short* __restrict__ WT, unsigned short* __restrict__ Z) {
  __shared__ unsigned short Sa[128 * 136];

  const int t = threadIdx.x, lane = t & 63, wave = t >> 6;
  const int l15 = lane & 15, lk = (lane >> 4) * 8;
  const int wm = (wave >> 1) * 64, wn = (wave & 1) * 64;
  const int mt = blockIdx.x, br = blockIdx.y;
  const int batch = mt >> 6, node0 = (mt & 63) * 128;

  {
    const int row = t >> 1, seg = (t & 1) * 64;
    if (AFP32) {
      const float4* src = (const float4*)(x + ((size_t)batch * 8192 + node0 + row) * 128 + seg);
      uint4* dst = (uint4*)&Sa[row * 136 + seg];
#pragma unroll
      for (int i = 0; i < 8; ++i) {
        float4 a = src[i * 2], b = src[i * 2 + 1];
        uint4 v;
        v.x = pack2(a.x, a.y); v.y = pack2(a.z, a.w);
        v.z = pack2(b.x, b.y); v.w = pack2(b.z, b.w);
        dst[i] = v;
      }
    } else {
      const uint4* src = (const uint4*)(H1m + ((size_t)(br * 4 + batch) * 8192 + node0 + row) * 128 + seg);
      uint4* dst = (uint4*)&Sa[row * 136 + seg];
#pragma unroll
      for (int i = 0; i < 8; ++i) dst[i] = src[i];
    }
  }
  __syncthreads();

  const unsigned short* WTb = WT + (size_t)(2 * br + (AFP32 ? 0 : 1)) * 16384;
  f32x4 acc[4][4];
#pragma unroll
  for (int i = 0; i < 4; ++i)
#pragma unroll
    for (int j = 0; j < 4; ++j) acc[i][j] = f32x4{0.f, 0.f, 0.f, 0.f};

#pragma unroll
  for (int kk = 0; kk < 4; ++kk) {
    bf16x8 av[4], wv[4];
#pragma unroll
    for (int mi = 0; mi < 4; ++mi)
      av[mi] = *(const bf16x8*)&Sa[(wm + mi * 16 + l15) * 136 + kk * 32 + lk];
#pragma unroll
    for (int ni = 0; ni < 4; ++ni)
      wv[ni] = *(const bf16x8*)&WTb[(wn + ni * 16 + l15) * 128 + kk * 32 + lk];
#pragma unroll
    for (int mi = 0; mi < 4; ++mi)
#pragma unroll
      for (int ni = 0; ni < 4; ++ni)
        acc[mi][ni] = __builtin_amdgcn_mfma_f32_16x16x32_bf16(av[mi], wv[ni], acc[mi][ni], 0, 0, 0);
  }

#pragma unroll
  for (int mi = 0; mi < 4; ++mi) {
#pragma unroll
    for (int ni = 0; ni < 4; ++ni) {
      const int row0 = wm + mi * 16 + (lane >> 4) * 4;
      const int col  = wn + ni * 16 + l15;
      uint2 pv;
      pv.x = pack2(acc[mi][ni][0], acc[mi][ni][1]);
      pv.y = pack2(acc[mi][ni][2], acc[mi][ni][3]);
      *(uint2*)(Z + ((size_t)br * 512 + batch * 128 + col) * 8192 + node0 + row0) = pv;
    }
  }
}

// ---------------------------------------------------------------- shared epilogue + args
struct BigArgs {
  const float* L[4];
  const float* bias[4];
  const unsigned short* Z;  // [br][512][8192] bf16 n-major
  void* Dst;                // LAYER0: H1 bf16 m-major; LAYER1: out fp32
};

#define MFMASET(AV0, AV1, AV2, AV3, BV0, BV1) do {                           \
    __builtin_amdgcn_s_setprio(1);                                           \
    c00 = __builtin_amdgcn_mfma_f32_32x32x16_bf16(AV0, BV0, c00, 0, 0, 0);   \
    c01 = __builtin_amdgcn_mfma_f32_32x32x16_bf16(AV0, BV1, c01, 0, 0, 0);   \
    c10 = __builtin_amdgcn_mfma_f32_32x32x16_bf16(AV1, BV0, c10, 0, 0, 0);   \
    c11 = __builtin_amdgcn_mfma_f32_32x32x16_bf16(AV1, BV1, c11, 0, 0, 0);   \
    c20 = __builtin_amdgcn_mfma_f32_32x32x16_bf16(AV2, BV0, c20, 0, 0, 0);   \
    c21 = __builtin_amdgcn_mfma_f32_32x32x16_bf16(AV2, BV1, c21, 0, 0, 0);   \
    c30 = __builtin_amdgcn_mfma_f32_32x32x16_bf16(AV3, BV0, c30, 0, 0, 0);   \
    c31 = __builtin_amdgcn_mfma_f32_32x32x16_bf16(AV3, BV1, c31, 0, 0, 0);   \
    __builtin_amdgcn_s_setprio(0); } while (0)

#define RDSET(ab_, bb_, s_, AV0, AV1, AV2, AV3, BV0, BV1) do {         \
    const int _ch = ((2 * (s_) + hk) ^ key4) * 16;                     \
    AV0 = *(const bf16x8*)((ab_) + aBase + _ch);                       \
    AV1 = *(const bf16x8*)((ab_) + aBase + 2048 + _ch);                \
    AV2 = *(const bf16x8*)((ab_) + aBase + 4096 + _ch);                \
    AV3 = *(const bf16x8*)((ab_) + aBase + 6144 + _ch);                \
    BV0 = *(const bf16x8*)((bb_) + bBase + _ch);                       \
    BV1 = *(const bf16x8*)((bb_) + bBase + 2048 + _ch); } while (0)

// epilogue used by both big variants
#define BIG_EPILOGUE()                                                                     \
  __syncthreads();                                                                          \
  if (LAYER == 0) {                                                                         \
    unsigned short* S16 = (unsigned short*)smem;                                            \
    _Pragma("unroll")                                                                       \
    for (int h = 0; h < 2; ++h) {                                                           \
      if (((wave >> 1) & 1) == h) {                                                         \
        EPI16(0, 0, c00); EPI16(0, 1, c01);                                                 \
        EPI16(1, 0, c10); EPI16(1, 1, c11);                                                 \
        EPI16(2, 0, c20); EPI16(2, 1, c21);                                                 \
        EPI16(3, 0, c30); EPI16(3, 1, c31);                                                 \
      }                                                                                     \
      __syncthreads();                                                                      \
      const int batch = nb * 2 + h;                                                         \
      const int row = t >> 1, seg = (t & 1) * 64;                                           \
      unsigned short* Dst = (unsigned short*)a.Dst;                                         \
      const uint4* src = (const uint4*)&S16[row * 136 + seg];                               \
      uint4* dst = (uint4*)(Dst + ((size_t)(br * 4 + batch) * 8192 + mbase + row) * 128 + seg); \
      _Pragma("unroll") for (int i = 0; i < 8; ++i) dst[i] = src[i];                        \
      __syncthreads();                                                                      \
    }                                                                                       \
  } else {                                                                                  \
    float* S32 = (float*)smem;                                                              \
    _Pragma("unroll")                                                                       \
    for (int h = 0; h < 2; ++h) {                                                           \
      _Pragma("unroll")                                                                     \
      for (int rh = 0; rh < 2; ++rh) {                                                      \
        if (((wave >> 1) & 1) == h && (wave >> 2) == rh) {                                  \
          EPI32(0, 0, c00); EPI32(0, 1, c01);                                               \
          EPI32(1, 0, c10); EPI32(1, 1, c11);                                               \
          EPI32(2, 0, c20); EPI32(2, 1, c21);                                               \
          EPI32(3, 0, c30); EPI32(3, 1, c31);                                               \
        }                                                                                   \
        __syncthreads();                                                                    \
        const int batch = nb * 2 + h;                                                       \
        const int row = t >> 2, seg = (t & 3) * 32;                                         \
        float* Dst = (float*)a.Dst;                                                         \
        const float4* src = (const float4*)&S32[row * 128 + seg];                           \
        float4* dst = (float4*)(Dst + ((size_t)(br * 4 + batch) * 8192 + mbase + rh * 128 + row) * 128 + seg); \
        _Pragma("unroll") for (int i = 0; i < 8; ++i) dst[i] = src[i];                      \
        __syncthreads();                                                                    \
      }                                                                                     \
    }                                                                                       \
  }

#define EPI16(AM, BN, ACC) do {                                             \
    const int col = (wave & 1) * 64 + (BN) * 32 + l31;                      \
    const float bvv = bias[col];                                            \
    _Pragma("unroll") for (int r = 0; r < 16; ++r) {                        \
      const int row = wm + (AM) * 32 + (r & 3) + 8 * (r >> 2) + 4 * hk;     \
      S16[row * 136 + col] = f2bf(fmaxf(ACC[r] + bvv, 0.f));                \
    } } while (0)
#define EPI32(AM, BN, ACC) do {                                             \
    const int col = (wave & 1) * 64 + (BN) * 32 + l31;                      \
    const float bvv = bias[col];                                            \
    _Pragma("unroll") for (int r = 0; r < 16; ++r) {                        \
      const int lrow = (AM) * 32 + (r & 3) + 8 * (r >> 2) + 4 * hk;         \
      S32[lrow * 128 + col] = fmaxf(ACC[r] + bvv, 0.f);                     \
    } } while (0)

// ---------------------------------------------------------------- big GEMM (pre-converted A)
// LDS: A ring 4x16KB @0, B ring 4x16KB @65536. One barrier/tile, vmcnt(8) pacing,
// 2-set k-step register pipeline (reads of both k-steps issued before MFMAs).
template <int LAYER>
__global__ __launch_bounds__(512)
void big_gemm_pc(BigArgs a, const char* __restrict__ Lbf) {
  extern __shared__ char smem[];

  const int t = threadIdx.x, lane = t & 63, wave = t >> 6;
  const int l31 = lane & 31, hk = lane >> 5;
  const int wm = (wave >> 2) * 128, wn = (wave & 3) * 64;

  const int bid = blockIdx.x;
  const int work = (bid & 7) * 32 + (bid >> 3);   // XCD-chunked, bijective
  const int nb = work & 1, mt = (work >> 1) & 31, br = work >> 6;
  const int mbase = mt * 256;

  const float* bias = a.bias[br];
  const unsigned short* Zb = a.Z + (size_t)br * (512 * 8192);

  const char* aTiles = Lbf + ((size_t)(br * 32 + mt) * 256) * 16384;
  const unsigned short* bG = Zb + (size_t)(nb * 256 + wave * 32 + (lane >> 2)) * 8192
                                + ((lane & 3) ^ ((lane >> 3) & 3)) * 8;

  const int aBase = (wm + l31) * 64;
  const int bBase = (wn + l31) * 64;
  const int key4 = (l31 >> 1) & 3;

  f32x16 c00{}, c01{}, c10{}, c11{}, c20{}, c21{}, c30{}, c31{};
  bf16x8 pa0, pa1, pa2, pa3, pb0, pb1;   // k-step 0 set
  bf16x8 qa0, qa1, qa2, qa3, qb0, qb1;   // k-step 1 set

#define STG(T_) do {                                                          \
    const char* _as = aTiles + (size_t)(T_) * 16384 + wave * 2048 + lane * 16;\
    char* _ad = smem + ((T_) & 3) * 16384 + wave * 2048;                      \
    GLOAD16(_as, _ad);                                                        \
    GLOAD16(_as + 1024, _ad + 1024);                                          \
    const unsigned short* _bp = bG + (size_t)(T_) * 32;                       \
    char* _bl = smem + 65536 + ((T_) & 3) * 16384 + wave * 2048;              \
    GLOAD16(_bp, _bl);                                                        \
    GLOAD16(_bp + 16 * 8192, _bl + 1024); } while (0)

#define ITER(T_, VMSTR, DO_STG) do {                                          \
    asm volatile("s_waitcnt " VMSTR ::: "memory");                            \
    __builtin_amdgcn_s_barrier();                                             \
    if (DO_STG) STG((T_) + 3);                                                \
    const char* _ab = smem + ((T_) & 3) * 16384;                              \
    const char* _bb = smem + 65536 + ((T_) & 3) * 16384;                      \
    RDSET(_ab, _bb, 0, pa0, pa1, pa2, pa3, pb0, pb1);                         \
    RDSET(_ab, _bb, 1, qa0, qa1, qa2, qa3, qb0, qb1);                         \
    MFMASET(pa0, pa1, pa2, pa3, pb0, pb1);                                    \
    MFMASET(qa0, qa1, qa2, qa3, qb0, qb1);                                    \
  } while (0)

  // prologue: groups 0,1,2 in flight (12 VMEM/thread)
  STG(0); STG(1); STG(2);

  for (int T = 0; T < 252; T += 4) {
    ITER(T,     "vmcnt(8)", 1);
    ITER(T + 1, "vmcnt(8)", 1);
    ITER(T + 2, "vmcnt(8)", 1);
    ITER(T + 3, "vmcnt(8)", 1);
  }
  ITER(252, "vmcnt(8)", 1);   // stages group 255
  ITER(253, "vmcnt(8)", 0);
  ITER(254, "vmcnt(4)", 0);
  ITER(255, "vmcnt(0)", 0);
#undef ITER
#undef STG

  BIG_EPILOGUE()
}

// ---------------------------------------------------------------- big GEMM (r8 fallback, reg-staged A)
template <int LAYER>
__global__ __launch_bounds__(512, 2)
void big_gemm_rs(BigArgs a) {
  extern __shared__ char smem[];

  const int t = threadIdx.x, lane = t & 63, wave = t >> 6;
  const int l31 = lane & 31, hk = lane >> 5;
  const int wm = (wave >> 2) * 128, wn = (wave & 3) * 64;

  const int bid = blockIdx.x;
  const int work = (bid & 7) * 32 + (bid >> 3);
  const int nb = work & 1, mt = (work >> 1) & 31, br = work >> 6;
  const int mbase = mt * 256;

  const float* A = a.L[br];
  const float* bias = a.bias[br];
  const unsigned short* Zb = a.Z + (size_t)br * (512 * 8192);

  const int arow = t >> 1, ah = t & 1;
  const float* aG = A + (size_t)(mbase + arow) * 8192 + ah * 16;
  const int c0 = 2 * ah, akey = (arow >> 1) & 3;
  char* aRowL = smem + arow * 64;
  const unsigned short* bG = Zb + (size_t)(nb * 256 + wave * 32 + (lane >> 2)) * 8192
                                + ((lane & 3) ^ ((lane >> 3) & 3)) * 8;
  char* bWave = smem + 32768 + wave * 2048;

  const int aBase = (wm + l31) * 64;
  const int bBase = (wn + l31) * 64;
  const int key4 = (l31 >> 1) & 3;

  f32x16 c00{}, c01{}, c10{}, c11{}, c20{}, c21{}, c30{}, c31{};
  float4 s0[4], s1[4], s2[4];
  bf16x8 pa0, pa1, pa2, pa3, pb0, pb1;
  bf16x8 qa0, qa1, qa2, qa3, qb0, qb1;

#define GLB(T_) do {                                                   \
    const unsigned short* _bp = bG + (size_t)(T_) * 32;                \
    char* _bl = bWave + ((T_) & 3) * 16384;                            \
    GLOAD16(_bp, _bl);                                                 \
    GLOAD16(_bp + 16 * 8192, _bl + 1024); } while (0)
#define LOADA(T_, R) do {                                              \
    const float* _ap = aG + (size_t)(T_) * 32;                         \
    R[0] = *(const float4*)(_ap);                                      \
    R[1] = *(const float4*)(_ap + 4);                                  \
    R[2] = *(const float4*)(_ap + 8);                                  \
    R[3] = *(const float4*)(_ap + 12); } while (0)
#define WRITEA(T_, R) do {                                             \
    char* _al = aRowL + (((T_) & 1)) * 16384;                          \
    *(bf16x8*)(_al + ((c0 ^ akey) * 16))       = cvt8(R[0], R[1]);     \
    *(bf16x8*)(_al + (((c0 + 1) ^ akey) * 16)) = cvt8(R[2], R[3]); } while (0)
#define ITER(T_, SLOAD, SWRITE, VMSTR, DO_STAGE, DO_WRITE) do {        \
    asm volatile("s_waitcnt " VMSTR ::: "memory");                     \
    asm volatile("s_waitcnt lgkmcnt(0)" ::: "memory");                 \
    __builtin_amdgcn_s_barrier();                                      \
    if (DO_STAGE) { GLB((T_) + 3); LOADA((T_) + 3, SLOAD); }           \
    const char* _ab = smem + ((T_) & 1) * 16384;                       \
    const char* _bb = smem + 32768 + ((T_) & 3) * 16384;               \
    RDSET(_ab, _bb, 0, pa0, pa1, pa2, pa3, pb0, pb1);                  \
    MFMASET(pa0, pa1, pa2, pa3, pb0, pb1);                             \
    if (DO_WRITE) WRITEA((T_) + 1, SWRITE);                            \
    RDSET(_ab, _bb, 1, qa0, qa1, qa2, qa3, qb0, qb1);                  \
    MFMASET(qa0, qa1, qa2, qa3, qb0, qb1);                             \
  } while (0)

  GLB(0); LOADA(0, s0);
  GLB(1); LOADA(1, s1);
  GLB(2); LOADA(2, s2);
  WRITEA(0, s0);

  for (int T = 0; T < 252; T += 3) {
    ITER(T,     s0, s1, "vmcnt(12)", 1, 1);
    ITER(T + 1, s1, s2, "vmcnt(12)", 1, 1);
    ITER(T + 2, s2, s0, "vmcnt(12)", 1, 1);
  }
  ITER(252, s0, s1, "vmcnt(12)", 1, 1);
  ITER(253, s0, s2, "vmcnt(12)", 0, 1);
  ITER(254, s0, s0, "vmcnt(6)",  0, 1);
  ITER(255, s0, s0, "vmcnt(0)",  0, 0);
#undef ITER
#undef WRITEA
#undef LOADA
#undef GLB

  BIG_EPILOGUE()
}

// ---------------------------------------------------------------- launch
extern "C" void kernel_launch(void* const* d_in, const int* in_sizes, int n_in,
                              void* d_out, int out_size, void* d_ws, size_t ws_size,
                              hipStream_t stream) {
  const float* x = (const float*)d_in[0];
  unsigned short* Z   = (unsigned short*)d_ws;               // [4][512][8192] bf16 (32 MiB)
  unsigned short* H1m = Z + (size_t)4 * 512 * 8192;          // [4][4][8192][128] bf16 (32 MiB)
  unsigned short* WT  = H1m + (size_t)4 * 4 * 8192 * 128;    // [8][128][128] bf16 (256 KiB)
  char* Lbf = (char*)(WT + 8 * 16384);                       // [4][32][256] 16KB tiles (512 MiB)
  float* out = (float*)d_out;

  const size_t NEED_PC = (size_t)33554432 + 33554432 + 262144 + 536870912;
  const bool use_pc = ws_size >= NEED_PC;

  static int attr_done = 0;
  if (!attr_done) {
    (void)hipFuncSetAttribute((const void*)big_gemm_pc<0>, hipFuncAttributeMaxDynamicSharedMemorySize, 131072);
    (void)hipFuncSetAttribute((const void*)big_gemm_pc<1>, hipFuncAttributeMaxDynamicSharedMemorySize, 131072);
    (void)hipFuncSetAttribute((const void*)big_gemm_rs<0>, hipFuncAttributeMaxDynamicSharedMemorySize, 98304);
    (void)hipFuncSetAttribute((const void*)big_gemm_rs<1>, hipFuncAttributeMaxDynamicSharedMemorySize, 98304);
    attr_done = 1;
  }

  WPtrs wp;
  for (int b = 0; b < 4; ++b) {
    wp.w[b * 2 + 0] = (const float*)d_in[5 + b * 4 + 0];
    wp.w[b * 2 + 1] = (const float*)d_in[5 + b * 4 + 2];
  }
  prep_w<<<8, 256, 0, stream>>>(wp, WT);

  BigArgs a0, a1;
  for (int b = 0; b < 4; ++b) {
    a0.L[b] = (const float*)d_in[1 + b];
    a1.L[b] = (const float*)d_in[1 + b];
    a0.bias[b] = (const float*)d_in[6 + b * 4];
    a1.bias[b] = (const float*)d_in[8 + b * 4];
  }
  a0.Z = Z; a0.Dst = (void*)H1m;
  a1.Z = Z; a1.Dst = (void*)out;

  if (use_pc) {
    LPtrs lp;
    for (int b = 0; b < 4; ++b) lp.l[b] = (const float*)d_in[1 + b];
    conv_l<<<dim3(128, 32, 4), 256, 0, stream>>>(lp, Lbf);
    small_gemm<1><<<dim3(256, 4), 256, 0, stream>>>(x, nullptr, WT, Z);
    big_gemm_pc<0><<<256, 512, 131072, stream>>>(a0, Lbf);
    small_gemm<0><<<dim3(256, 4), 256, 0, stream>>>(nullptr, H1m, WT, Z);
    big_gemm_pc<1><<<256, 512, 131072, stream>>>(a1, Lbf);
  } else {
    small_gemm<1><<<dim3(256, 4), 256, 0, stream>>>(x, nullptr, WT, Z);
    big_gemm_rs<0><<<256, 512, 98304, stream>>>(a0);
    small_gemm<0><<<dim3(256, 4), 256, 0, stream>>>(nullptr, H1m, WT, Z);
    big_gemm_rs<1><<<256, 512, 98304, stream>>>(a1);
  }
}

// Round 12
// 911.614 us; speedup vs baseline: 1.9479x; 1.0143x over previous
//
#include <hip/hip_runtime.h>
#include <stdint.h>

// GCN multi-branch, round 12.
// relu((L@x)@W+b) == relu(L@(x@W)+b). Pipeline (pc path):
//   conv_l: L fp32 -> bf16 tile images (contiguous DRAM for big A-stage)
//   small<1>: Z = x@W0
//   big<0>: H1 = relu(L@Z+b0); FUSED epilogue: Z2 = H1@W1 (n-major) -- small<0> deleted
//   big<1>: out = relu(L@Z2+b1) fp32
// big K-loop: m201-style 2-phase/tile rhythm {reads; stage; [vmcnt(8)]; barrier;
// lgkm(0); setprio MFMA; barrier}, 4-slot A+B LDS rings, 32x32x16 MFMA.

typedef short bf16x8 __attribute__((ext_vector_type(8)));
typedef float f32x4  __attribute__((ext_vector_type(4)));
typedef unsigned int u32x4 __attribute__((ext_vector_type(4)));
typedef float f32x16 __attribute__((ext_vector_type(16)));

static __device__ __forceinline__ unsigned short f2bf(float f) {
  __bf16 h = (__bf16)f;
  return __builtin_bit_cast(unsigned short, h);
}
static __device__ __forceinline__ unsigned int pack2(float a, float b) {
  return (unsigned int)f2bf(a) | ((unsigned int)f2bf(b) << 16);
}
static __device__ __forceinline__ bf16x8 cvt8(float4 lo, float4 hi) {
  bf16x8 r;
  r[0] = (short)f2bf(lo.x); r[1] = (short)f2bf(lo.y);
  r[2] = (short)f2bf(lo.z); r[3] = (short)f2bf(lo.w);
  r[4] = (short)f2bf(hi.x); r[5] = (short)f2bf(hi.y);
  r[6] = (short)f2bf(hi.z); r[7] = (short)f2bf(hi.w);
  return r;
}

#define GLOAD16(g, l)                                                                  \
  __builtin_amdgcn_global_load_lds((const __attribute__((address_space(1))) void*)(g), \
                                   (__attribute__((address_space(3))) void*)(l), 16, 0, 0)

// ---------------------------------------------------------------- prep: W[fi][fo] -> WT bf16 [fo][fi]
struct WPtrs { const float* w[8]; };
__global__ __launch_bounds__(256)
void prep_w(WPtrs p, unsigned short* __restrict__ wt) {
  const int s = blockIdx.x;
  const float* W = p.w[s];
  unsigned short* dst = wt + s * 16384;
  for (int i = threadIdx.x; i < 16384; i += 256) {
    const int fi = i >> 7, fo = i & 127;
    dst[fo * 128 + fi] = f2bf(W[i]);
  }
}

// ---------------------------------------------------------------- conv: L fp32 -> bf16 tile images
struct LPtrs { const float* l[4]; };
__global__ __launch_bounds__(256)
void conv_l(LPtrs p, char* __restrict__ lbf) {
  __shared__ char T[32768];  // [ktl 8][rr 64][64B]
  const int t = threadIdx.x, lane = t & 63, wave = t >> 6;
  const int rg = blockIdx.x, kg = blockIdx.y, br = blockIdx.z;
  const float* L = p.l[br];
  const int r0 = rg * 64, k0 = kg * 256;
  const int mt = rg >> 2, rowoff = (rg & 3) * 64, kt0 = kg * 8;
#pragma unroll
  for (int i = 0; i < 16; ++i) {
    const int rr = wave * 16 + i;
    const f32x4* src = (const f32x4*)(L + (size_t)(r0 + rr) * 8192 + k0);
    f32x4 v = __builtin_nontemporal_load(src + lane);
    const int ktl = lane >> 3;
    const int ch  = ((lane >> 1) & 3) ^ ((rr >> 1) & 3);
    uint2 pv; pv.x = pack2(v[0], v[1]); pv.y = pack2(v[2], v[3]);
    *(uint2*)(T + ktl * 4096 + rr * 64 + ch * 16 + (lane & 1) * 8) = pv;
  }
  __syncthreads();
  char* dstb = lbf + ((size_t)(br * 32 + mt) * 256 + kt0) * 16384 + rowoff * 64;
#pragma unroll
  for (int ktl = 0; ktl < 8; ++ktl) {
    u32x4 v = ((const u32x4*)(T + ktl * 4096))[t];
    __builtin_nontemporal_store(v, (u32x4*)(dstb + (size_t)ktl * 16384) + t);
  }
}

// ---------------------------------------------------------------- small GEMM: Z = A @ W  (K=128)
template <int AFP32>
__global__ __launch_bounds__(256)
void small_gemm(const float* __restrict__ x, const unsigned short* __restrict__ H1m,
                const unsigned short* __restrict__ WT, unsigned short* __restrict__ Z) {
  __shared__ unsigned short Sa[128 * 136];

  const int t = threadIdx.x, lane = t & 63, wave = t >> 6;
  const int l15 = lane & 15, lk = (lane >> 4) * 8;
  const int wm = (wave >> 1) * 64, wn = (wave & 1) * 64;
  const int mt = blockIdx.x, br = blockIdx.y;
  const int batch = mt >> 6, node0 = (mt & 63) * 128;

  {
    const int row = t >> 1, seg = (t & 1) * 64;
    if (AFP32) {
      const float4* src = (const float4*)(x + ((size_t)batch * 8192 + node0 + row) * 128 + seg);
      uint4* dst = (uint4*)&Sa[row * 136 + seg];
#pragma unroll
      for (int i = 0; i < 8; ++i) {
        float4 a = src[i * 2], b = src[i * 2 + 1];
        uint4 v;
        v.x = pack2(a.x, a.y); v.y = pack2(a.z, a.w);
        v.z = pack2(b.x, b.y); v.w = pack2(b.z, b.w);
        dst[i] = v;
      }
    } else {
      const uint4* src = (const uint4*)(H1m + ((size_t)(br * 4 + batch) * 8192 + node0 + row) * 128 + seg);
      uint4* dst = (uint4*)&Sa[row * 136 + seg];
#pragma unroll
      for (int i = 0; i < 8; ++i) dst[i] = src[i];
    }
  }
  __syncthreads();

  const unsigned short* WTb = WT + (size_t)(2 * br + (AFP32 ? 0 : 1)) * 16384;
  f32x4 acc[4][4];
#pragma unroll
  for (int i = 0; i < 4; ++i)
#pragma unroll
    for (int j = 0; j < 4; ++j) acc[i][j] = f32x4{0.f, 0.f, 0.f, 0.f};

#pragma unroll
  for (int kk = 0; kk < 4; ++kk) {
    bf16x8 av[4], wv[4];
#pragma unroll
    for (int mi = 0; mi < 4; ++mi)
      av[mi] = *(const bf16x8*)&Sa[(wm + mi * 16 + l15) * 136 + kk * 32 + lk];
#pragma unroll
    for (int ni = 0; ni < 4; ++ni)
      wv[ni] = *(const bf16x8*)&WTb[(wn + ni * 16 + l15) * 128 + kk * 32 + lk];
#pragma unroll
    for (int mi = 0; mi < 4; ++mi)
#pragma unroll
      for (int ni = 0; ni < 4; ++ni)
        acc[mi][ni] = __builtin_amdgcn_mfma_f32_16x16x32_bf16(av[mi], wv[ni], acc[mi][ni], 0, 0, 0);
  }

#pragma unroll
  for (int mi = 0; mi < 4; ++mi) {
#pragma unroll
    for (int ni = 0; ni < 4; ++ni) {
      const int row0 = wm + mi * 16 + (lane >> 4) * 4;
      const int col  = wn + ni * 16 + l15;
      uint2 pv;
      pv.x = pack2(acc[mi][ni][0], acc[mi][ni][1]);
      pv.y = pack2(acc[mi][ni][2], acc[mi][ni][3]);
      *(uint2*)(Z + ((size_t)br * 512 + batch * 128 + col) * 8192 + node0 + row0) = pv;
    }
  }
}

// ---------------------------------------------------------------- shared pieces
struct BigArgs {
  const float* L[4];
  const float* bias[4];
  const unsigned short* Z;      // B operand, [br][512][8192] bf16 n-major
  const unsigned short* WTall;  // [8][128][128]; LAYER0 fused epilogue uses (2br+1)
  void* Dst;                    // LAYER0: Z2 bf16 n-major; LAYER1: out fp32
};

#define MFMASET(AV0, AV1, AV2, AV3, BV0, BV1) do {                           \
    __builtin_amdgcn_s_setprio(1);                                           \
    c00 = __builtin_amdgcn_mfma_f32_32x32x16_bf16(AV0, BV0, c00, 0, 0, 0);   \
    c01 = __builtin_amdgcn_mfma_f32_32x32x16_bf16(AV0, BV1, c01, 0, 0, 0);   \
    c10 = __builtin_amdgcn_mfma_f32_32x32x16_bf16(AV1, BV0, c10, 0, 0, 0);   \
    c11 = __builtin_amdgcn_mfma_f32_32x32x16_bf16(AV1, BV1, c11, 0, 0, 0);   \
    c20 = __builtin_amdgcn_mfma_f32_32x32x16_bf16(AV2, BV0, c20, 0, 0, 0);   \
    c21 = __builtin_amdgcn_mfma_f32_32x32x16_bf16(AV2, BV1, c21, 0, 0, 0);   \
    c30 = __builtin_amdgcn_mfma_f32_32x32x16_bf16(AV3, BV0, c30, 0, 0, 0);   \
    c31 = __builtin_amdgcn_mfma_f32_32x32x16_bf16(AV3, BV1, c31, 0, 0, 0);   \
    __builtin_amdgcn_s_setprio(0); } while (0)

#define RDSET(ab_, bb_, s_, AV0, AV1, AV2, AV3, BV0, BV1) do {         \
    const int _ch = ((2 * (s_) + hk) ^ key4) * 16;                     \
    AV0 = *(const bf16x8*)((ab_) + aBase + _ch);                       \
    AV1 = *(const bf16x8*)((ab_) + aBase + 2048 + _ch);                \
    AV2 = *(const bf16x8*)((ab_) + aBase + 4096 + _ch);                \
    AV3 = *(const bf16x8*)((ab_) + aBase + 6144 + _ch);                \
    BV0 = *(const bf16x8*)((bb_) + bBase + _ch);                       \
    BV1 = *(const bf16x8*)((bb_) + bBase + 2048 + _ch); } while (0)

#define EPI16(AM, BN, ACC) do {                                             \
    const int col = (wave & 1) * 64 + (BN) * 32 + l31;                      \
    const float bvv = bias[col];                                            \
    _Pragma("unroll") for (int r = 0; r < 16; ++r) {                        \
      const int row = wm + (AM) * 32 + (r & 3) + 8 * (r >> 2) + 4 * hk;     \
      S16[row * 136 + col] = f2bf(fmaxf(ACC[r] + bvv, 0.f));                \
    } } while (0)
#define EPI32(AM, BN, ACC) do {                                             \
    const int col = (wave & 1) * 64 + (BN) * 32 + l31;                      \
    const float bvv = bias[col];                                            \
    _Pragma("unroll") for (int r = 0; r < 16; ++r) {                        \
      const int lrow = (AM) * 32 + (r & 3) + 8 * (r >> 2) + 4 * hk;         \
      S32[lrow * 128 + col] = fmaxf(ACC[r] + bvv, 0.f);                     \
    } } while (0)

// ---------------------------------------------------------------- big GEMM (pre-converted A)
template <int LAYER>
__global__ __launch_bounds__(512)
void big_gemm_pc(BigArgs a, const char* __restrict__ Lbf) {
  extern __shared__ char smem[];

  const int t = threadIdx.x, lane = t & 63, wave = t >> 6;
  const int l31 = lane & 31, hk = lane >> 5;
  const int wm = (wave >> 2) * 128, wn = (wave & 3) * 64;

  const int bid = blockIdx.x;
  const int work = (bid & 7) * 32 + (bid >> 3);   // XCD-chunked, bijective
  const int nb = work & 1, mt = (work >> 1) & 31, br = work >> 6;
  const int mbase = mt * 256;

  const float* bias = a.bias[br];
  const unsigned short* Zb = a.Z + (size_t)br * (512 * 8192);

  const char* aTiles = Lbf + ((size_t)(br * 32 + mt) * 256) * 16384;
  const unsigned short* bG = Zb + (size_t)(nb * 256 + wave * 32 + (lane >> 2)) * 8192
                                + ((lane & 3) ^ ((lane >> 3) & 3)) * 8;

  const int aBase = (wm + l31) * 64;
  const int bBase = (wn + l31) * 64;
  const int key4 = (l31 >> 1) & 3;

  f32x16 c00{}, c01{}, c10{}, c11{}, c20{}, c21{}, c30{}, c31{};
  bf16x8 pa0, pa1, pa2, pa3, pb0, pb1;

#define STGA(T_) do {                                                          \
    const char* _as = aTiles + (size_t)(T_) * 16384 + wave * 2048 + lane * 16; \
    char* _ad = smem + ((T_) & 3) * 16384 + wave * 2048;                       \
    GLOAD16(_as, _ad);                                                         \
    GLOAD16(_as + 1024, _ad + 1024); } while (0)
#define STGB(T_) do {                                                          \
    const unsigned short* _bp = bG + (size_t)(T_) * 32;                        \
    char* _bl = smem + 65536 + ((T_) & 3) * 16384 + wave * 2048;               \
    GLOAD16(_bp, _bl);                                                         \
    GLOAD16(_bp + 16 * 8192, _bl + 1024); } while (0)

  // m201-style phase: {reads; stage; [vmcnt]; barrier; lgkm(0); prio MFMA; barrier}
#define PH(T_, S_, STG_, VM_) do {                                             \
    const char* _ab = smem + ((T_) & 3) * 16384;                               \
    const char* _bb = smem + 65536 + ((T_) & 3) * 16384;                       \
    RDSET(_ab, _bb, S_, pa0, pa1, pa2, pa3, pb0, pb1);                         \
    STG_;                                                                      \
    VM_;                                                                       \
    __builtin_amdgcn_s_barrier();                                              \
    asm volatile("s_waitcnt lgkmcnt(0)" ::: "memory");                         \
    MFMASET(pa0, pa1, pa2, pa3, pb0, pb1);                                     \
    __builtin_amdgcn_s_barrier();                                              \
  } while (0)

#define VM8  asm volatile("s_waitcnt vmcnt(8)" ::: "memory")
#define VM4  asm volatile("s_waitcnt vmcnt(4)" ::: "memory")
#define VM0  asm volatile("s_waitcnt vmcnt(0)" ::: "memory")

  // prologue: tiles 0,1,2 staged (12 loads/thread); force tile 0, sync
  STGA(0); STGB(0); STGA(1); STGB(1); STGA(2); STGB(2);
  VM8;
  __builtin_amdgcn_s_barrier();

  for (int T = 0; T < 252; ++T) {
    PH(T, 0, STGA(T + 3), (void)0);
    PH(T, 1, STGB(T + 3), VM8);   // forces tile T+1 (12 outstanding -> oldest 4)
  }
  PH(252, 0, STGA(255), (void)0);
  PH(252, 1, STGB(255), VM8);     // forces 253
  PH(253, 0, (void)0, (void)0);
  PH(253, 1, (void)0, VM4);       // forces 254
  PH(254, 0, (void)0, (void)0);
  PH(254, 1, (void)0, VM0);       // forces 255
  PH(255, 0, (void)0, (void)0);
  PH(255, 1, (void)0, (void)0);
#undef PH
#undef STGA
#undef STGB

  // ---------------- epilogue ----------------
  __syncthreads();

  if (LAYER == 0) {
    // S16 = relu(H1 tile + b0); then FUSED: Z2 = S16 @ W1, written n-major.
    unsigned short* S16 = (unsigned short*)smem;  // [256][136] bf16, 69632 B
    const unsigned short* W1 = a.WTall + (size_t)(2 * br + 1) * 16384;  // [fo'][fi]
    unsigned short* Zo = (unsigned short*)a.Dst;
    const int wm2 = (wave >> 2) * 128;   // W-GEMM wave split: 2M x 4N over 256x128
    const int wn2 = (wave & 3) * 32;
#pragma unroll
    for (int h = 0; h < 2; ++h) {
      if (((wave >> 1) & 1) == h) {
        EPI16(0, 0, c00); EPI16(0, 1, c01);
        EPI16(1, 0, c10); EPI16(1, 1, c11);
        EPI16(2, 0, c20); EPI16(2, 1, c21);
        EPI16(3, 0, c30); EPI16(3, 1, c31);
      }
      __syncthreads();
      // W-GEMM: [256 node][128 fi] @ [128 fi][128 fo'] -> z[4] (4 m-frags x 1 n-frag)
      f32x16 z0{}, z1{}, z2{}, z3{};
#pragma unroll
      for (int ks = 0; ks < 8; ++ks) {
        const int ko = ks * 32 + hk * 16;  // byte offset of 8 bf16 k-slice
        const char* sb = (const char*)S16;
        bf16x8 sa0 = *(const bf16x8*)(sb + (wm2 + l31) * 272 + ko);
        bf16x8 sa1 = *(const bf16x8*)(sb + (wm2 + 32 + l31) * 272 + ko);
        bf16x8 sa2 = *(const bf16x8*)(sb + (wm2 + 64 + l31) * 272 + ko);
        bf16x8 sa3 = *(const bf16x8*)(sb + (wm2 + 96 + l31) * 272 + ko);
        bf16x8 wv  = *(const bf16x8*)((const char*)W1 + (wn2 + l31) * 256 + ko);
        z0 = __builtin_amdgcn_mfma_f32_32x32x16_bf16(sa0, wv, z0, 0, 0, 0);
        z1 = __builtin_amdgcn_mfma_f32_32x32x16_bf16(sa1, wv, z1, 0, 0, 0);
        z2 = __builtin_amdgcn_mfma_f32_32x32x16_bf16(sa2, wv, z2, 0, 0, 0);
        z3 = __builtin_amdgcn_mfma_f32_32x32x16_bf16(sa3, wv, z3, 0, 0, 0);
      }
      const int batch = nb * 2 + h;
      const int fo = wn2 + l31;
      unsigned short* colp = Zo + ((size_t)(br * 512 + batch * 128) + fo) * 8192
                                + mbase + wm2;
#pragma unroll
      for (int g = 0; g < 4; ++g) {
        const int rb = 8 * g + 4 * hk;
        uint2 p0, p1, p2, p3;
        p0.x = pack2(z0[4 * g], z0[4 * g + 1]); p0.y = pack2(z0[4 * g + 2], z0[4 * g + 3]);
        p1.x = pack2(z1[4 * g], z1[4 * g + 1]); p1.y = pack2(z1[4 * g + 2], z1[4 * g + 3]);
        p2.x = pack2(z2[4 * g], z2[4 * g + 1]); p2.y = pack2(z2[4 * g + 2], z2[4 * g + 3]);
        p3.x = pack2(z3[4 * g], z3[4 * g + 1]); p3.y = pack2(z3[4 * g + 2], z3[4 * g + 3]);
        *(uint2*)(colp + rb)      = p0;
        *(uint2*)(colp + 32 + rb) = p1;
        *(uint2*)(colp + 64 + rb) = p2;
        *(uint2*)(colp + 96 + rb) = p3;
      }
      __syncthreads();
    }
  } else {
    float* S32 = (float*)smem;  // [128][128] fp32 per pass, 4 passes
#pragma unroll
    for (int h = 0; h < 2; ++h) {
#pragma unroll
      for (int rh = 0; rh < 2; ++rh) {
        if (((wave >> 1) & 1) == h && (wave >> 2) == rh) {
          EPI32(0, 0, c00); EPI32(0, 1, c01);
          EPI32(1, 0, c10); EPI32(1, 1, c11);
          EPI32(2, 0, c20); EPI32(2, 1, c21);
          EPI32(3, 0, c30); EPI32(3, 1, c31);
        }
        __syncthreads();
        const int batch = nb * 2 + h;
        const int row = t >> 2, seg = (t & 3) * 32;
        float* Dst = (float*)a.Dst;
        const float4* src = (const float4*)&S32[row * 128 + seg];
        float4* dst = (float4*)(Dst + ((size_t)(br * 4 + batch) * 8192 + mbase + rh * 128 + row) * 128 + seg);
#pragma unroll
        for (int i = 0; i < 8; ++i) dst[i] = src[i];
        __syncthreads();
      }
    }
  }
}

// ---------------------------------------------------------------- big GEMM (r8 fallback, reg-staged A)
template <int LAYER>
__global__ __launch_bounds__(512, 2)
void big_gemm_rs(BigArgs a) {
  extern __shared__ char smem[];

  const int t = threadIdx.x, lane = t & 63, wave = t >> 6;
  const int l31 = lane & 31, hk = lane >> 5;
  const int wm = (wave >> 2) * 128, wn = (wave & 3) * 64;

  const int bid = blockIdx.x;
  const int work = (bid & 7) * 32 + (bid >> 3);
  const int nb = work & 1, mt = (work >> 1) & 31, br = work >> 6;
  const int mbase = mt * 256;

  const float* A = a.L[br];
  const float* bias = a.bias[br];
  const unsigned short* Zb = a.Z + (size_t)br * (512 * 8192);

  const int arow = t >> 1, ah = t & 1;
  const float* aG = A + (size_t)(mbase + arow) * 8192 + ah * 16;
  const int c0 = 2 * ah, akey = (arow >> 1) & 3;
  char* aRowL = smem + arow * 64;
  const unsigned short* bG = Zb + (size_t)(nb * 256 + wave * 32 + (lane >> 2)) * 8192
                                + ((lane & 3) ^ ((lane >> 3) & 3)) * 8;
  char* bWave = smem + 32768 + wave * 2048;

  const int aBase = (wm + l31) * 64;
  const int bBase = (wn + l31) * 64;
  const int key4 = (l31 >> 1) & 3;

  f32x16 c00{}, c01{}, c10{}, c11{}, c20{}, c21{}, c30{}, c31{};
  float4 s0[4], s1[4], s2[4];
  bf16x8 pa0, pa1, pa2, pa3, pb0, pb1;
  bf16x8 qa0, qa1, qa2, qa3, qb0, qb1;

#define GLB(T_) do {                                                   \
    const unsigned short* _bp = bG + (size_t)(T_) * 32;                \
    char* _bl = bWave + ((T_) & 3) * 16384;                            \
    GLOAD16(_bp, _bl);                                                 \
    GLOAD16(_bp + 16 * 8192, _bl + 1024); } while (0)
#define LOADA(T_, R) do {                                              \
    const float* _ap = aG + (size_t)(T_) * 32;                         \
    R[0] = *(const float4*)(_ap);                                      \
    R[1] = *(const float4*)(_ap + 4);                                  \
    R[2] = *(const float4*)(_ap + 8);                                  \
    R[3] = *(const float4*)(_ap + 12); } while (0)
#define WRITEA(T_, R) do {                                             \
    char* _al = aRowL + (((T_) & 1)) * 16384;                          \
    *(bf16x8*)(_al + ((c0 ^ akey) * 16))       = cvt8(R[0], R[1]);     \
    *(bf16x8*)(_al + (((c0 + 1) ^ akey) * 16)) = cvt8(R[2], R[3]); } while (0)
#define ITER(T_, SLOAD, SWRITE, VMSTR, DO_STAGE, DO_WRITE) do {        \
    asm volatile("s_waitcnt " VMSTR ::: "memory");                     \
    asm volatile("s_waitcnt lgkmcnt(0)" ::: "memory");                 \
    __builtin_amdgcn_s_barrier();                                      \
    if (DO_STAGE) { GLB((T_) + 3); LOADA((T_) + 3, SLOAD); }           \
    const char* _ab = smem + ((T_) & 1) * 16384;                       \
    const char* _bb = smem + 32768 + ((T_) & 3) * 16384;               \
    RDSET(_ab, _bb, 0, pa0, pa1, pa2, pa3, pb0, pb1);                  \
    MFMASET(pa0, pa1, pa2, pa3, pb0, pb1);                             \
    if (DO_WRITE) WRITEA((T_) + 1, SWRITE);                            \
    RDSET(_ab, _bb, 1, qa0, qa1, qa2, qa3, qb0, qb1);                  \
    MFMASET(qa0, qa1, qa2, qa3, qb0, qb1);                             \
  } while (0)

  GLB(0); LOADA(0, s0);
  GLB(1); LOADA(1, s1);
  GLB(2); LOADA(2, s2);
  WRITEA(0, s0);

  for (int T = 0; T < 252; T += 3) {
    ITER(T,     s0, s1, "vmcnt(12)", 1, 1);
    ITER(T + 1, s1, s2, "vmcnt(12)", 1, 1);
    ITER(T + 2, s2, s0, "vmcnt(12)", 1, 1);
  }
  ITER(252, s0, s1, "vmcnt(12)", 1, 1);
  ITER(253, s0, s2, "vmcnt(12)", 0, 1);
  ITER(254, s0, s0, "vmcnt(6)",  0, 1);
  ITER(255, s0, s0, "vmcnt(0)",  0, 0);
#undef ITER
#undef WRITEA
#undef LOADA
#undef GLB

  __syncthreads();
  if (LAYER == 0) {
    unsigned short* S16 = (unsigned short*)smem;
#pragma unroll
    for (int h = 0; h < 2; ++h) {
      if (((wave >> 1) & 1) == h) {
        EPI16(0, 0, c00); EPI16(0, 1, c01);
        EPI16(1, 0, c10); EPI16(1, 1, c11);
        EPI16(2, 0, c20); EPI16(2, 1, c21);
        EPI16(3, 0, c30); EPI16(3, 1, c31);
      }
      __syncthreads();
      const int batch = nb * 2 + h;
      const int row = t >> 1, seg = (t & 1) * 64;
      unsigned short* Dst = (unsigned short*)a.Dst;  // H1m m-major
      const uint4* src = (const uint4*)&S16[row * 136 + seg];
      uint4* dst = (uint4*)(Dst + ((size_t)(br * 4 + batch) * 8192 + mbase + row) * 128 + seg);
#pragma unroll
      for (int i = 0; i < 8; ++i) dst[i] = src[i];
      __syncthreads();
    }
  } else {
    float* S32 = (float*)smem;
#pragma unroll
    for (int h = 0; h < 2; ++h) {
#pragma unroll
      for (int rh = 0; rh < 2; ++rh) {
        if (((wave >> 1) & 1) == h && (wave >> 2) == rh) {
          EPI32(0, 0, c00); EPI32(0, 1, c01);
          EPI32(1, 0, c10); EPI32(1, 1, c11);
          EPI32(2, 0, c20); EPI32(2, 1, c21);
          EPI32(3, 0, c30); EPI32(3, 1, c31);
        }
        __syncthreads();
        const int batch = nb * 2 + h;
        const int row = t >> 2, seg = (t & 3) * 32;
        float* Dst = (float*)a.Dst;
        const float4* src = (const float4*)&S32[row * 128 + seg];
        float4* dst = (float4*)(Dst + ((size_t)(br * 4 + batch) * 8192 + mbase + rh * 128 + row) * 128 + seg);
#pragma unroll
        for (int i = 0; i < 8; ++i) dst[i] = src[i];
        __syncthreads();
      }
    }
  }
}

// ---------------------------------------------------------------- launch
extern "C" void kernel_launch(void* const* d_in, const int* in_sizes, int n_in,
                              void* d_out, int out_size, void* d_ws, size_t ws_size,
                              hipStream_t stream) {
  const float* x = (const float*)d_in[0];
  unsigned short* Z   = (unsigned short*)d_ws;               // [4][512][8192] bf16 (32 MiB)
  unsigned short* Z2  = Z + (size_t)4 * 512 * 8192;          // 32 MiB (pc: Z2; fallback: H1m)
  unsigned short* WT  = Z2 + (size_t)4 * 512 * 8192;         // [8][128][128] bf16 (256 KiB)
  char* Lbf = (char*)(WT + 8 * 16384);                       // 512 MiB tile images
  float* out = (float*)d_out;

  const size_t NEED_PC = (size_t)33554432 + 33554432 + 262144 + 536870912;
  const bool use_pc = ws_size >= NEED_PC;

  static int attr_done = 0;
  if (!attr_done) {
    (void)hipFuncSetAttribute((const void*)big_gemm_pc<0>, hipFuncAttributeMaxDynamicSharedMemorySize, 131072);
    (void)hipFuncSetAttribute((const void*)big_gemm_pc<1>, hipFuncAttributeMaxDynamicSharedMemorySize, 131072);
    (void)hipFuncSetAttribute((const void*)big_gemm_rs<0>, hipFuncAttributeMaxDynamicSharedMemorySize, 98304);
    (void)hipFuncSetAttribute((const void*)big_gemm_rs<1>, hipFuncAttributeMaxDynamicSharedMemorySize, 98304);
    attr_done = 1;
  }

  WPtrs wp;
  for (int b = 0; b < 4; ++b) {
    wp.w[b * 2 + 0] = (const float*)d_in[5 + b * 4 + 0];
    wp.w[b * 2 + 1] = (const float*)d_in[5 + b * 4 + 2];
  }
  prep_w<<<8, 256, 0, stream>>>(wp, WT);

  BigArgs a0, a1;
  for (int b = 0; b < 4; ++b) {
    a0.L[b] = (const float*)d_in[1 + b];
    a1.L[b] = (const float*)d_in[1 + b];
    a0.bias[b] = (const float*)d_in[6 + b * 4];
    a1.bias[b] = (const float*)d_in[8 + b * 4];
  }
  a0.WTall = WT; a1.WTall = WT;

  if (use_pc) {
    LPtrs lp;
    for (int b = 0; b < 4; ++b) lp.l[b] = (const float*)d_in[1 + b];
    conv_l<<<dim3(128, 32, 4), 256, 0, stream>>>(lp, Lbf);
    small_gemm<1><<<dim3(256, 4), 256, 0, stream>>>(x, nullptr, WT, Z);
    a0.Z = Z;  a0.Dst = (void*)Z2;   // fused epilogue writes Z2 = H1@W1
    a1.Z = Z2; a1.Dst = (void*)out;
    big_gemm_pc<0><<<256, 512, 131072, stream>>>(a0, Lbf);
    big_gemm_pc<1><<<256, 512, 131072, stream>>>(a1, Lbf);
  } else {
    unsigned short* H1m = Z2;
    a0.Z = Z; a0.Dst = (void*)H1m;
    a1.Z = Z; a1.Dst = (void*)out;
    small_gemm<1><<<dim3(256, 4), 256, 0, stream>>>(x, nullptr, WT, Z);
    big_gemm_rs<0><<<256, 512, 98304, stream>>>(a0);
    small_gemm<0><<<dim3(256, 4), 256, 0, stream>>>(nullptr, H1m, WT, Z);
    big_gemm_rs<1><<<256, 512, 98304, stream>>>(a1);
  }
}